// Round 1
// baseline (1447.781 us; speedup 1.0000x reference)
//
#include <hip/hip_runtime.h>
#include <math.h>

namespace {
constexpr int B_ = 2, C_ = 128, H_ = 48, W_ = 48;
constexpr int L_ = H_ * W_;        // 2304
constexpr int BL_ = B_ * L_;       // 4608
constexpr int D_ = 256, N_ = 16, R_ = 8, K_ = 4;
}

// ---------------------------------------------------------------------------
// 1) LayerNorm over channels: x (B,C,H,W) -> xn (B*L, C) channels-last
// block: 256 threads handles 16 positions; grid (L/16, B)
__global__ void k_ln(const float* __restrict__ x, const float* __restrict__ g,
                     const float* __restrict__ bt, float* __restrict__ xn) {
    int b = blockIdx.y;
    int pos0 = blockIdx.x * 16;
    __shared__ float tile[C_ * 17];  // [c][pp] padded
    int t = threadIdx.x;
    for (int i = 0; i < 8; i++) {
        int idx = t + i * 256;
        int c = idx >> 4, pp = idx & 15;
        tile[c * 17 + pp] = x[(b * C_ + c) * L_ + pos0 + pp];
    }
    __syncthreads();
    int p = t >> 4, lane16 = t & 15;
    float s = 0.f, s2 = 0.f;
#pragma unroll
    for (int i = 0; i < 8; i++) {
        int c = lane16 * 8 + i;
        float v = tile[c * 17 + p];
        s += v; s2 += v * v;
    }
#pragma unroll
    for (int off = 8; off; off >>= 1) {
        s += __shfl_xor(s, off, 64);
        s2 += __shfl_xor(s2, off, 64);
    }
    float mu = s * (1.f / C_);
    float var = s2 * (1.f / C_) - mu * mu;
    float rstd = rsqrtf(var + 1e-6f);
#pragma unroll
    for (int i = 0; i < 8; i++) {
        int c = lane16 * 8 + i;
        float v = tile[c * 17 + p];
        xn[(b * L_ + pos0 + p) * C_ + c] = (v - mu) * rstd * g[c] + bt[c];
    }
}

// ---------------------------------------------------------------------------
// 2) Generic f32 GEMM: Cout(M,N) = A(M,K) * Wt(N,K)^T + bias, optional relu
// BM=BN=64, BK=16, 256 threads each 4x4. grid (N/64, M/64)
template <int ACT>
__global__ void k_gemm(const float* __restrict__ A, const float* __restrict__ Wt,
                       const float* __restrict__ bias, float* __restrict__ Cout,
                       int M, int Nc, int Kc) {
    const int BM = 64, BN = 64, BK = 16;
    __shared__ float As[BK][BM + 1];
    __shared__ float Ws[BK][BN + 1];
    int m0 = blockIdx.y * BM, n0 = blockIdx.x * BN;
    int t = threadIdx.x;
    int tx = t & 15, ty = t >> 4;
    float acc[4][4] = {};
    for (int k0 = 0; k0 < Kc; k0 += BK) {
#pragma unroll
        for (int i = 0; i < 4; i++) {
            int idx = t + i * 256;
            int m = idx >> 4, kk = idx & 15;
            As[kk][m] = A[(m0 + m) * Kc + k0 + kk];
            Ws[kk][m] = Wt[(n0 + m) * Kc + k0 + kk];
        }
        __syncthreads();
#pragma unroll
        for (int kk = 0; kk < BK; kk++) {
            float a[4], bb[4];
#pragma unroll
            for (int i = 0; i < 4; i++) a[i] = As[kk][i * 16 + ty];
#pragma unroll
            for (int j = 0; j < 4; j++) bb[j] = Ws[kk][j * 16 + tx];
#pragma unroll
            for (int i = 0; i < 4; i++)
#pragma unroll
                for (int j = 0; j < 4; j++) acc[i][j] += a[i] * bb[j];
        }
        __syncthreads();
    }
#pragma unroll
    for (int i = 0; i < 4; i++) {
        int m = m0 + i * 16 + ty;
#pragma unroll
        for (int j = 0; j < 4; j++) {
            int n = n0 + j * 16 + tx;
            float v = acc[i][j] + bias[n];
            if (ACT == 1) v = fmaxf(v, 0.f);
            Cout[m * Nc + n] = v;
        }
    }
}

// ---------------------------------------------------------------------------
// 3) depthwise 3x3 conv + bias + SiLU on xm (= xz[..., :256]) -> xcl (B,L,D) d-contig
// grid (D/64, H, B), block 256
__global__ void k_dwconv(const float* __restrict__ xz, const float* __restrict__ cw,
                         const float* __restrict__ cb, float* __restrict__ xcl) {
    int d0 = blockIdx.x * 64;
    int h = blockIdx.y;
    int b = blockIdx.z;
    __shared__ float tile[3][W_][64];  // 36 KB
    int t = threadIdx.x;
    for (int rr = 0; rr < 3; rr++) {
        int hh = h - 1 + rr;
        for (int i = 0; i < 12; i++) {
            int idx = t + i * 256;
            int w = idx >> 6, dd = idx & 63;
            float v = 0.f;
            if (hh >= 0 && hh < H_) v = xz[(size_t)((b * L_ + hh * W_ + w)) * 512 + d0 + dd];
            tile[rr][w][dd] = v;
        }
    }
    __syncthreads();
    int dd = t & 63, wg = t >> 6;
    int d = d0 + dd;
    float w9[9];
#pragma unroll
    for (int i = 0; i < 9; i++) w9[i] = cw[d * 9 + i];
    float bias = cb[d];
    for (int w = wg; w < W_; w += 4) {
        float s = 0.f;
#pragma unroll
        for (int rr = 0; rr < 3; rr++)
#pragma unroll
            for (int c2 = 0; c2 < 3; c2++) {
                int ww = w - 1 + c2;
                float v = (ww >= 0 && ww < W_) ? tile[rr][ww][dd] : 0.f;
                s += v * w9[rr * 3 + c2];
            }
        s += bias;
        float sig = 1.f / (1.f + expf(-s));
        xcl[(b * L_ + h * W_ + w) * D_ + d] = s * sig;
    }
}

// ---------------------------------------------------------------------------
// 4) x_proj einsum + dt_proj + softplus for one (b,k,l) per block
// grid (L, K, B), block 256
__global__ void k_xproj(const float* __restrict__ xcl, const float* __restrict__ xpw,
                        const float* __restrict__ dtw, const float* __restrict__ dtb,
                        float* __restrict__ dts, float* __restrict__ Bs,
                        float* __restrict__ Cs) {
    int l = blockIdx.x, k = blockIdx.y, b = blockIdx.z;
    int l2 = (k >= 2) ? (L_ - 1 - l) : l;
    int pos = (k & 1) ? ((l2 % H_) * W_ + l2 / H_) : l2;
    __shared__ float xrow[D_];
    __shared__ float xdbl[40];
    int t = threadIdx.x;
    xrow[t] = xcl[(b * L_ + pos) * D_ + t];
    __syncthreads();
    if (t < 40) {
        const float* wp = xpw + (k * 40 + t) * D_;
        float s = 0.f;
        for (int d2 = 0; d2 < D_; d2++) s += xrow[d2] * wp[d2];
        xdbl[t] = s;
    }
    __syncthreads();
    {
        float s = dtb[k * D_ + t];
        const float* dw = dtw + (k * D_ + t) * R_;
#pragma unroll
        for (int r = 0; r < R_; r++) s += xdbl[r] * dw[r];
        float sp = (s > 20.f) ? s : log1pf(expf(s));
        dts[((size_t)(b * K_ + k) * L_ + l) * D_ + t] = sp;
    }
    if (t < N_)
        Bs[((size_t)(b * K_ + k) * L_ + l) * N_ + t] = xdbl[R_ + t];
    else if (t < 2 * N_)
        Cs[((size_t)(b * K_ + k) * L_ + l) * N_ + (t - N_)] = xdbl[R_ + N_ + (t - N_)];
}

// ---------------------------------------------------------------------------
// 5) selective scan. thread = (d-group, n); block 256 = 16 d x 16 n
// grid (D/16, K, B)
__global__ void k_scan(const float* __restrict__ dts, const float* __restrict__ Bs,
                       const float* __restrict__ Cs, const float* __restrict__ xcl,
                       const float* __restrict__ A_log, float* __restrict__ ys) {
    const int DG = 16, CH = 64;
    int d0 = blockIdx.x * DG;
    int k = blockIdx.y;
    int b = blockIdx.z;
    int t = threadIdx.x;
    int dg = t >> 4, n = t & 15;
    int d = d0 + dg;
    float Adn = -expf(A_log[(k * D_ + d) * N_ + n]);
    float h = 0.f;
    __shared__ float s_dt[CH][DG], s_x[CH][DG], s_B[CH][N_], s_C[CH][N_], s_y[CH][DG];
    const float* dts_bk = dts + (size_t)(b * K_ + k) * L_ * D_;
    const float* Bs_bk = Bs + (size_t)(b * K_ + k) * L_ * N_;
    const float* Cs_bk = Cs + (size_t)(b * K_ + k) * L_ * N_;
    float* ys_bk = ys + (size_t)(b * K_ + k) * L_ * D_;
    for (int l0 = 0; l0 < L_; l0 += CH) {
#pragma unroll
        for (int i = 0; i < 4; i++) {
            int idx = t + i * 256;
            int ll = idx >> 4, dd = idx & 15;
            int l = l0 + ll;
            s_dt[ll][dd] = dts_bk[(size_t)l * D_ + d0 + dd];
            int l2 = (k >= 2) ? (L_ - 1 - l) : l;
            int pos = (k & 1) ? ((l2 % H_) * W_ + l2 / H_) : l2;
            s_x[ll][dd] = xcl[(b * L_ + pos) * D_ + d0 + dd];
            s_B[ll][dd] = Bs_bk[(size_t)l * N_ + dd];
            s_C[ll][dd] = Cs_bk[(size_t)l * N_ + dd];
        }
        __syncthreads();
        for (int ll = 0; ll < CH; ll++) {
            float dt = s_dt[ll][dg];
            float xv = s_x[ll][dg];
            float a = expf(dt * Adn);
            h = h * a + dt * xv * s_B[ll][n];
            float yp = h * s_C[ll][n];
            yp += __shfl_xor(yp, 1, 64);
            yp += __shfl_xor(yp, 2, 64);
            yp += __shfl_xor(yp, 4, 64);
            yp += __shfl_xor(yp, 8, 64);
            if (n == 0) s_y[ll][dg] = yp;
        }
        __syncthreads();
#pragma unroll
        for (int i = 0; i < 4; i++) {
            int idx = t + i * 256;
            int ll = idx >> 4, dd = idx & 15;
            ys_bk[(size_t)(l0 + ll) * D_ + d0 + dd] = s_y[ll][dd];
        }
        __syncthreads();
    }
}

// ---------------------------------------------------------------------------
// 6) combine 4 directions + D*x skip + out-LayerNorm + silu(z) gate -> yln (BL,D)
// grid BL, block 256 (one per d)
__global__ void k_combine(const float* __restrict__ ys, const float* __restrict__ xcl,
                          const float* __restrict__ Ds, const float* __restrict__ xz,
                          const float* __restrict__ g, const float* __restrict__ bt,
                          float* __restrict__ yln) {
    int bp = blockIdx.x;
    int b = bp / L_, pos = bp % L_;
    int t = threadIdx.x;
    int hh = pos / W_, ww = pos % W_;
    int l0 = pos;
    int l1 = ww * H_ + hh;
    int l2 = L_ - 1 - pos;
    int l3 = L_ - 1 - l1;
    size_t base = (size_t)b * K_ * L_ * D_;
    float v = ys[base + ((size_t)0 * L_ + l0) * D_ + t]
            + ys[base + ((size_t)1 * L_ + l1) * D_ + t]
            + ys[base + ((size_t)2 * L_ + l2) * D_ + t]
            + ys[base + ((size_t)3 * L_ + l3) * D_ + t];
    float dsum = Ds[0 * D_ + t] + Ds[1 * D_ + t] + Ds[2 * D_ + t] + Ds[3 * D_ + t];
    v += dsum * xcl[(b * L_ + pos) * D_ + t];

    __shared__ float red[8];
    float s = v, s2 = v * v;
#pragma unroll
    for (int off = 32; off; off >>= 1) {
        s += __shfl_xor(s, off, 64);
        s2 += __shfl_xor(s2, off, 64);
    }
    int wv = t >> 6;
    if ((t & 63) == 0) { red[wv] = s; red[4 + wv] = s2; }
    __syncthreads();
    s = red[0] + red[1] + red[2] + red[3];
    s2 = red[4] + red[5] + red[6] + red[7];
    float mu = s * (1.f / D_);
    float var = s2 * (1.f / D_) - mu * mu;
    float rstd = rsqrtf(var + 1e-6f);
    float ln = (v - mu) * rstd * g[t] + bt[t];
    float z = xz[(size_t)(b * L_ + pos) * 512 + 256 + t];
    float sig = 1.f / (1.f + expf(-z));
    yln[(b * L_ + pos) * D_ + t] = ln * z * sig;
}

// ---------------------------------------------------------------------------
// 8) flash attention with q=k=v, nh=4, dh=32. grid (L/64, nh, B), block 256
__global__ void k_attn(const float* __restrict__ xo, float* __restrict__ xo2) {
    const int TQ = 64, TK = 64, DH = 32;
    int q0 = blockIdx.x * TQ;
    int hG = blockIdx.y;
    int b = blockIdx.z;
    __shared__ float Qs[TQ][DH + 1];
    __shared__ float Ks[TK][DH + 1];
    __shared__ float Ps[TQ][TK + 1];
    int t = threadIdx.x;
    int r = t >> 2, g = t & 3;
#pragma unroll
    for (int i = 0; i < 8; i++) {
        int idx = t + i * 256;
        int row = idx >> 5, e = idx & 31;
        Qs[row][e] = xo[(size_t)(b * L_ + q0 + row) * C_ + hG * DH + e];
    }
    __syncthreads();
    float qr[DH];
#pragma unroll
    for (int e = 0; e < DH; e++) qr[e] = Qs[r][e];
    float o[8] = {0.f, 0.f, 0.f, 0.f, 0.f, 0.f, 0.f, 0.f};
    float m = -1e30f, lsum = 0.f;
    const float scale = 0.17677669529663687f;  // 1/sqrt(32)
    for (int kt = 0; kt < L_; kt += TK) {
#pragma unroll
        for (int i = 0; i < 8; i++) {
            int idx = t + i * 256;
            int row = idx >> 5, e = idx & 31;
            Ks[row][e] = xo[(size_t)(b * L_ + kt + row) * C_ + hG * DH + e];
        }
        __syncthreads();
        float sv[16];
        float rmax = -1e30f;
#pragma unroll
        for (int c = 0; c < 16; c++) {
            int cc = g * 16 + c;
            float s = 0.f;
#pragma unroll
            for (int e = 0; e < DH; e++) s += qr[e] * Ks[cc][e];
            s *= scale;
            sv[c] = s;
            rmax = fmaxf(rmax, s);
        }
        rmax = fmaxf(rmax, __shfl_xor(rmax, 1, 64));
        rmax = fmaxf(rmax, __shfl_xor(rmax, 2, 64));
        float mnew = fmaxf(m, rmax);
        float alpha = expf(m - mnew);
        float psum = 0.f;
#pragma unroll
        for (int c = 0; c < 16; c++) {
            float p = expf(sv[c] - mnew);
            Ps[r][g * 16 + c] = p;
            psum += p;
        }
        psum += __shfl_xor(psum, 1, 64);
        psum += __shfl_xor(psum, 2, 64);
        lsum = lsum * alpha + psum;
        m = mnew;
#pragma unroll
        for (int i = 0; i < 8; i++) o[i] *= alpha;
        __syncthreads();
        for (int c = 0; c < TK; c++) {
            float p = Ps[r][c];
#pragma unroll
            for (int i = 0; i < 8; i++) o[i] += p * Ks[c][g * 8 + i];
        }
        __syncthreads();
    }
    float inv = 1.f / lsum;
#pragma unroll
    for (int i = 0; i < 8; i++) {
        xo2[(size_t)(b * L_ + q0 + r) * C_ + hG * DH + g * 8 + i] = o[i] * inv;
    }
}

// ---------------------------------------------------------------------------
// 10) ghost cheap branch: depthwise 3x3 on p + relu; assemble output + residual
// grid (H, B), block 256
__global__ void k_ghost2(const float* __restrict__ pcl, const float* __restrict__ g2w,
                         const float* __restrict__ g2b, const float* __restrict__ x,
                         float* __restrict__ out) {
    int h = blockIdx.x, b = blockIdx.y;
    __shared__ float tile[3][W_][64];
    int t = threadIdx.x;
    for (int rr = 0; rr < 3; rr++) {
        int hh = h - 1 + rr;
        for (int i = 0; i < 12; i++) {
            int idx = t + i * 256;
            int w = idx >> 6, cc = idx & 63;
            tile[rr][w][cc] = (hh >= 0 && hh < H_) ? pcl[(size_t)(b * L_ + hh * W_ + w) * 64 + cc] : 0.f;
        }
    }
    __syncthreads();
    int cc = t & 63, wg = t >> 6;
    float w9[9];
#pragma unroll
    for (int i = 0; i < 9; i++) w9[i] = g2w[cc * 9 + i];
    float bias = g2b[cc];
    for (int w = wg; w < W_; w += 4) {
        int pos = h * W_ + w;
        float pv = tile[1][w][cc];
        out[(size_t)(b * C_ + cc) * L_ + pos] = pv + x[(size_t)(b * C_ + cc) * L_ + pos];
        float s = bias;
#pragma unroll
        for (int rr = 0; rr < 3; rr++)
#pragma unroll
            for (int c2 = 0; c2 < 3; c2++) {
                int ww = w - 1 + c2;
                if (ww >= 0 && ww < W_) s += tile[rr][ww][cc] * w9[rr * 3 + c2];
            }
        s = fmaxf(s, 0.f);
        out[(size_t)(b * C_ + 64 + cc) * L_ + pos] = s + x[(size_t)(b * C_ + 64 + cc) * L_ + pos];
    }
}

// ---------------------------------------------------------------------------
extern "C" void kernel_launch(void* const* d_in, const int* in_sizes, int n_in,
                              void* d_out, int out_size, void* d_ws, size_t ws_size,
                              hipStream_t stream) {
    const float* x        = (const float*)d_in[0];
    const float* norm_g   = (const float*)d_in[1];
    const float* norm_b   = (const float*)d_in[2];
    const float* in_w     = (const float*)d_in[3];
    const float* in_b     = (const float*)d_in[4];
    const float* conv_w   = (const float*)d_in[5];
    const float* conv_b   = (const float*)d_in[6];
    const float* xpw      = (const float*)d_in[7];
    const float* dtw      = (const float*)d_in[8];
    const float* dtb      = (const float*)d_in[9];
    const float* A_log    = (const float*)d_in[10];
    const float* Ds       = (const float*)d_in[11];
    const float* out_g    = (const float*)d_in[12];
    const float* out_b    = (const float*)d_in[13];
    const float* opw      = (const float*)d_in[14];
    const float* opb      = (const float*)d_in[15];
    const float* g1w      = (const float*)d_in[16];
    const float* g1b      = (const float*)d_in[17];
    const float* g2w      = (const float*)d_in[18];
    const float* g2b      = (const float*)d_in[19];
    float* out = (float*)d_out;

    float* ws = (float*)d_ws;
    size_t off = 0;
    float* xn  = ws + off; off += (size_t)BL_ * C_;        // 589824
    float* xz  = ws + off; off += (size_t)BL_ * 2 * D_;    // 2359296
    float* xcl = ws + off; off += (size_t)BL_ * D_;        // 1179648
    float* dts = ws + off; off += (size_t)B_ * K_ * L_ * D_;  // 4718592
    float* Bss = ws + off; off += (size_t)B_ * K_ * L_ * N_;  // 294912
    float* Css = ws + off; off += (size_t)B_ * K_ * L_ * N_;  // 294912
    float* ys  = ws + off; off += (size_t)B_ * K_ * L_ * D_;  // 4718592
    float* yln = ws + off; off += (size_t)BL_ * D_;        // 1179648
    float* xo  = ws + off; off += (size_t)BL_ * C_;        // 589824
    float* xo2 = ws + off; off += (size_t)BL_ * C_;        // 589824
    float* pcl = ws + off; off += (size_t)BL_ * 64;        // 294912

    k_ln<<<dim3(L_ / 16, B_), 256, 0, stream>>>(x, norm_g, norm_b, xn);
    k_gemm<0><<<dim3(512 / 64, BL_ / 64), 256, 0, stream>>>(xn, in_w, in_b, xz, BL_, 512, C_);
    k_dwconv<<<dim3(D_ / 64, H_, B_), 256, 0, stream>>>(xz, conv_w, conv_b, xcl);
    k_xproj<<<dim3(L_, K_, B_), 256, 0, stream>>>(xcl, xpw, dtw, dtb, dts, Bss, Css);
    k_scan<<<dim3(D_ / 16, K_, B_), 256, 0, stream>>>(dts, Bss, Css, xcl, A_log, ys);
    k_combine<<<dim3(BL_), 256, 0, stream>>>(ys, xcl, Ds, xz, out_g, out_b, yln);
    k_gemm<0><<<dim3(C_ / 64, BL_ / 64), 256, 0, stream>>>(yln, opw, opb, xo, BL_, C_, D_);
    k_attn<<<dim3(L_ / 64, 4, B_), 256, 0, stream>>>(xo, xo2);
    k_gemm<1><<<dim3(1, BL_ / 64), 256, 0, stream>>>(xo2, g1w, g1b, pcl, BL_, 64, C_);
    k_ghost2<<<dim3(H_, B_), 256, 0, stream>>>(pcl, g2w, g2b, x, out);
}

// Round 2
// 477.443 us; speedup vs baseline: 3.0324x; 3.0324x over previous
//
#include <hip/hip_runtime.h>
#include <math.h>

namespace {
constexpr int B_ = 2, C_ = 128, H_ = 48, W_ = 48;
constexpr int L_ = H_ * W_;        // 2304
constexpr int BL_ = B_ * L_;       // 4608
constexpr int D_ = 256, N_ = 16, R_ = 8, K_ = 4;
constexpr int S_ = 16, SEG_ = 144; // scan segments
}

typedef __attribute__((ext_vector_type(8))) short sh8;
typedef __attribute__((ext_vector_type(4))) float f4;

__device__ inline short f2bf(float x) {
    unsigned u = __float_as_uint(x);
    unsigned r = (u + 0x7fff + ((u >> 16) & 1)) >> 16;
    return (short)r;
}

// ---------------------------------------------------------------------------
// 1) LayerNorm over channels: x (B,C,H,W) -> xn (B*L, C) channels-last
__global__ void k_ln(const float* __restrict__ x, const float* __restrict__ g,
                     const float* __restrict__ bt, float* __restrict__ xn) {
    int b = blockIdx.y;
    int pos0 = blockIdx.x * 16;
    __shared__ float tile[C_ * 17];
    int t = threadIdx.x;
    for (int i = 0; i < 8; i++) {
        int idx = t + i * 256;
        int c = idx >> 4, pp = idx & 15;
        tile[c * 17 + pp] = x[(b * C_ + c) * L_ + pos0 + pp];
    }
    __syncthreads();
    int p = t >> 4, lane16 = t & 15;
    float s = 0.f, s2 = 0.f;
#pragma unroll
    for (int i = 0; i < 8; i++) {
        int c = lane16 * 8 + i;
        float v = tile[c * 17 + p];
        s += v; s2 += v * v;
    }
#pragma unroll
    for (int off = 8; off; off >>= 1) {
        s += __shfl_xor(s, off, 64);
        s2 += __shfl_xor(s2, off, 64);
    }
    float mu = s * (1.f / C_);
    float var = s2 * (1.f / C_) - mu * mu;
    float rstd = rsqrtf(var + 1e-6f);
#pragma unroll
    for (int i = 0; i < 8; i++) {
        int c = lane16 * 8 + i;
        float v = tile[c * 17 + p];
        xn[(b * L_ + pos0 + p) * C_ + c] = (v - mu) * rstd * g[c] + bt[c];
    }
}

// ---------------------------------------------------------------------------
// 2) f32 GEMM with N-guards: Cout(M,N) = A(M,K)*Wt(N,K)^T (+bias) (opt relu)
template <int ACT, bool BIAS>
__global__ void k_gemm(const float* __restrict__ A, const float* __restrict__ Wt,
                       const float* __restrict__ bias, float* __restrict__ Cout,
                       int M, int Nc, int Kc) {
    const int BM = 64, BN = 64, BK = 16;
    __shared__ float As[BK][BM + 1];
    __shared__ float Ws[BK][BN + 1];
    int m0 = blockIdx.y * BM, n0 = blockIdx.x * BN;
    int t = threadIdx.x;
    int tx = t & 15, ty = t >> 4;
    float acc[4][4] = {};
    for (int k0 = 0; k0 < Kc; k0 += BK) {
#pragma unroll
        for (int i = 0; i < 4; i++) {
            int idx = t + i * 256;
            int m = idx >> 4, kk = idx & 15;
            As[kk][m] = A[(size_t)(m0 + m) * Kc + k0 + kk];
            Ws[kk][m] = (n0 + m < Nc) ? Wt[(size_t)(n0 + m) * Kc + k0 + kk] : 0.f;
        }
        __syncthreads();
#pragma unroll
        for (int kk = 0; kk < BK; kk++) {
            float a[4], bb[4];
#pragma unroll
            for (int i = 0; i < 4; i++) a[i] = As[kk][i * 16 + ty];
#pragma unroll
            for (int j = 0; j < 4; j++) bb[j] = Ws[kk][j * 16 + tx];
#pragma unroll
            for (int i = 0; i < 4; i++)
#pragma unroll
                for (int j = 0; j < 4; j++) acc[i][j] += a[i] * bb[j];
        }
        __syncthreads();
    }
#pragma unroll
    for (int i = 0; i < 4; i++) {
        int m = m0 + i * 16 + ty;
#pragma unroll
        for (int j = 0; j < 4; j++) {
            int n = n0 + j * 16 + tx;
            if (n < Nc) {
                float v = acc[i][j];
                if (BIAS) v += bias[n];
                if (ACT == 1) v = fmaxf(v, 0.f);
                Cout[(size_t)m * Nc + n] = v;
            }
        }
    }
}

// ---------------------------------------------------------------------------
// 3) depthwise 3x3 conv + bias + SiLU -> xcl (B,L,D) d-contig
__global__ void k_dwconv(const float* __restrict__ xz, const float* __restrict__ cw,
                         const float* __restrict__ cb, float* __restrict__ xcl) {
    int d0 = blockIdx.x * 64;
    int h = blockIdx.y;
    int b = blockIdx.z;
    __shared__ float tile[3][W_][64];
    int t = threadIdx.x;
    for (int rr = 0; rr < 3; rr++) {
        int hh = h - 1 + rr;
        for (int i = 0; i < 12; i++) {
            int idx = t + i * 256;
            int w = idx >> 6, dd = idx & 63;
            float v = 0.f;
            if (hh >= 0 && hh < H_) v = xz[(size_t)((b * L_ + hh * W_ + w)) * 512 + d0 + dd];
            tile[rr][w][dd] = v;
        }
    }
    __syncthreads();
    int dd = t & 63, wg = t >> 6;
    int d = d0 + dd;
    float w9[9];
#pragma unroll
    for (int i = 0; i < 9; i++) w9[i] = cw[d * 9 + i];
    float bias = cb[d];
    for (int w = wg; w < W_; w += 4) {
        float s = 0.f;
#pragma unroll
        for (int rr = 0; rr < 3; rr++)
#pragma unroll
            for (int c2 = 0; c2 < 3; c2++) {
                int ww = w - 1 + c2;
                float v = (ww >= 0 && ww < W_) ? tile[rr][ww][dd] : 0.f;
                s += v * w9[rr * 3 + c2];
            }
        s += bias;
        float sig = 1.f / (1.f + expf(-s));
        xcl[(b * L_ + h * W_ + w) * D_ + d] = s * sig;
    }
}

// ---------------------------------------------------------------------------
// 4b) gather P4 (B*L,160) at permuted pos -> dts (softplus), Bs, Cs
__global__ void k_xproj2(const float* __restrict__ P4, const float* __restrict__ dtw,
                         const float* __restrict__ dtb, float* __restrict__ dts,
                         float* __restrict__ Bss, float* __restrict__ Css) {
    int l = blockIdx.x, k = blockIdx.y, b = blockIdx.z;
    int l2 = (k >= 2) ? (L_ - 1 - l) : l;
    int pos = (k & 1) ? ((l2 % H_) * W_ + l2 / H_) : l2;
    __shared__ float xdbl[40];
    int t = threadIdx.x;
    if (t < 40) xdbl[t] = P4[((size_t)(b * L_ + pos)) * 160 + k * 40 + t];
    __syncthreads();
    float s = dtb[k * D_ + t];
    const float* dw = dtw + ((size_t)k * D_ + t) * R_;
#pragma unroll
    for (int r = 0; r < R_; r++) s += xdbl[r] * dw[r];
    float sp = (s > 20.f) ? s : log1pf(expf(s));
    dts[((size_t)(b * K_ + k) * L_ + l) * D_ + t] = sp;
    if (t < N_)
        Bss[((size_t)(b * K_ + k) * L_ + l) * N_ + t] = xdbl[R_ + t];
    else if (t < 2 * N_)
        Css[((size_t)(b * K_ + k) * L_ + l) * N_ + (t - N_)] = xdbl[R_ + N_ + (t - N_)];
}

// ---------------------------------------------------------------------------
// 5a) scan pass A: per-segment local scan -> h_end, sum(dt)
__global__ void k_scan_a(const float* __restrict__ dts, const float* __restrict__ Bss,
                         const float* __restrict__ xcl, const float* __restrict__ A_log,
                         float* __restrict__ hend, float* __restrict__ sumdt) {
    int d0 = blockIdx.x * 16;
    int ks = blockIdx.y;
    int k = ks >> 4, s = ks & 15;
    int b = blockIdx.z;
    int t = threadIdx.x;
    int dg = t >> 4, n = t & 15;
    int d = d0 + dg;
    float Adn = -expf(A_log[(k * D_ + d) * N_ + n]);
    __shared__ float s_dt[SEG_][16], s_x[SEG_][16], s_B[SEG_][16];
    int l0 = s * SEG_;
    const float* dts_bk = dts + ((size_t)(b * K_ + k) * L_ + l0) * D_;
    const float* Bs_bk = Bss + ((size_t)(b * K_ + k) * L_ + l0) * N_;
#pragma unroll
    for (int i = 0; i < 9; i++) {
        int idx = t + i * 256;
        int ll = idx >> 4, dd = idx & 15;
        s_dt[ll][dd] = dts_bk[(size_t)ll * D_ + d0 + dd];
        s_B[ll][dd] = Bs_bk[(size_t)ll * N_ + dd];
        int l = l0 + ll;
        int l2 = (k >= 2) ? (L_ - 1 - l) : l;
        int pos = (k & 1) ? ((l2 % H_) * W_ + l2 / H_) : l2;
        s_x[ll][dd] = xcl[(b * L_ + pos) * D_ + d0 + dd];
    }
    __syncthreads();
    float h = 0.f, sd = 0.f;
    for (int ll = 0; ll < SEG_; ll++) {
        float dt = s_dt[ll][dg];
        float a = expf(dt * Adn);
        h = h * a + dt * s_x[ll][dg] * s_B[ll][n];
        sd += dt;
    }
    hend[(((size_t)(b * K_ + k) * S_ + s) * D_ + d) * N_ + n] = h;
    if (n == 0) sumdt[((size_t)(b * K_ + k) * S_ + s) * D_ + d] = sd;
}

// 5b) cross-segment prefix: h_in per segment
__global__ void k_scan_b(const float* __restrict__ hend, const float* __restrict__ sumdt,
                         const float* __restrict__ A_log, float* __restrict__ hin) {
    int gid = blockIdx.x * 256 + threadIdx.x;  // 32768
    int n = gid & 15, d = (gid >> 4) & 255, k = (gid >> 12) & 3, b = gid >> 14;
    float Adn = -expf(A_log[(k * D_ + d) * N_ + n]);
    float h = 0.f;
    for (int s = 0; s < S_; s++) {
        size_t idx = (((size_t)(b * K_ + k) * S_ + s) * D_ + d) * N_ + n;
        hin[idx] = h;
        float P = expf(Adn * sumdt[((size_t)(b * K_ + k) * S_ + s) * D_ + d]);
        h = hend[idx] + P * h;
    }
}

// 5c) scan pass C: replay with h0 = hin, emit y
__global__ void k_scan_c(const float* __restrict__ dts, const float* __restrict__ Bss,
                         const float* __restrict__ Css, const float* __restrict__ xcl,
                         const float* __restrict__ A_log, const float* __restrict__ hin,
                         float* __restrict__ ys) {
    int d0 = blockIdx.x * 16;
    int ks = blockIdx.y;
    int k = ks >> 4, s = ks & 15;
    int b = blockIdx.z;
    int t = threadIdx.x;
    int dg = t >> 4, n = t & 15;
    int d = d0 + dg;
    float Adn = -expf(A_log[(k * D_ + d) * N_ + n]);
    __shared__ float s_dt[SEG_][16], s_x[SEG_][16], s_B[SEG_][16], s_C[SEG_][16], s_y[SEG_][16];
    int l0 = s * SEG_;
    const float* dts_bk = dts + ((size_t)(b * K_ + k) * L_ + l0) * D_;
    const float* Bs_bk = Bss + ((size_t)(b * K_ + k) * L_ + l0) * N_;
    const float* Cs_bk = Css + ((size_t)(b * K_ + k) * L_ + l0) * N_;
#pragma unroll
    for (int i = 0; i < 9; i++) {
        int idx = t + i * 256;
        int ll = idx >> 4, dd = idx & 15;
        s_dt[ll][dd] = dts_bk[(size_t)ll * D_ + d0 + dd];
        s_B[ll][dd] = Bs_bk[(size_t)ll * N_ + dd];
        s_C[ll][dd] = Cs_bk[(size_t)ll * N_ + dd];
        int l = l0 + ll;
        int l2 = (k >= 2) ? (L_ - 1 - l) : l;
        int pos = (k & 1) ? ((l2 % H_) * W_ + l2 / H_) : l2;
        s_x[ll][dd] = xcl[(b * L_ + pos) * D_ + d0 + dd];
    }
    __syncthreads();
    float h = hin[(((size_t)(b * K_ + k) * S_ + s) * D_ + d) * N_ + n];
    for (int ll = 0; ll < SEG_; ll++) {
        float dt = s_dt[ll][dg];
        float a = expf(dt * Adn);
        h = h * a + dt * s_x[ll][dg] * s_B[ll][n];
        float yp = h * s_C[ll][n];
        yp += __shfl_xor(yp, 1, 64);
        yp += __shfl_xor(yp, 2, 64);
        yp += __shfl_xor(yp, 4, 64);
        yp += __shfl_xor(yp, 8, 64);
        if (n == 0) s_y[ll][dg] = yp;
    }
    __syncthreads();
    float* ys_bk = ys + ((size_t)(b * K_ + k) * L_ + l0) * D_;
#pragma unroll
    for (int i = 0; i < 9; i++) {
        int idx = t + i * 256;
        int ll = idx >> 4, dd = idx & 15;
        ys_bk[(size_t)ll * D_ + d0 + dd] = s_y[ll][dd];
    }
}

// ---------------------------------------------------------------------------
// 6) combine 4 directions + D*x + out-LN + silu(z) gate
__global__ void k_combine(const float* __restrict__ ys, const float* __restrict__ xcl,
                          const float* __restrict__ Ds, const float* __restrict__ xz,
                          const float* __restrict__ g, const float* __restrict__ bt,
                          float* __restrict__ yln) {
    int bp = blockIdx.x;
    int b = bp / L_, pos = bp % L_;
    int t = threadIdx.x;
    int hh = pos / W_, ww = pos % W_;
    int l0 = pos;
    int l1 = ww * H_ + hh;
    int l2 = L_ - 1 - pos;
    int l3 = L_ - 1 - l1;
    size_t base = (size_t)b * K_ * L_ * D_;
    float v = ys[base + ((size_t)0 * L_ + l0) * D_ + t]
            + ys[base + ((size_t)1 * L_ + l1) * D_ + t]
            + ys[base + ((size_t)2 * L_ + l2) * D_ + t]
            + ys[base + ((size_t)3 * L_ + l3) * D_ + t];
    float dsum = Ds[0 * D_ + t] + Ds[1 * D_ + t] + Ds[2 * D_ + t] + Ds[3 * D_ + t];
    v += dsum * xcl[(b * L_ + pos) * D_ + t];

    __shared__ float red[8];
    float s = v, s2 = v * v;
#pragma unroll
    for (int off = 32; off; off >>= 1) {
        s += __shfl_xor(s, off, 64);
        s2 += __shfl_xor(s2, off, 64);
    }
    int wv = t >> 6;
    if ((t & 63) == 0) { red[wv] = s; red[4 + wv] = s2; }
    __syncthreads();
    s = red[0] + red[1] + red[2] + red[3];
    s2 = red[4] + red[5] + red[6] + red[7];
    float mu = s * (1.f / D_);
    float var = s2 * (1.f / D_) - mu * mu;
    float rstd = rsqrtf(var + 1e-6f);
    float ln = (v - mu) * rstd * g[t] + bt[t];
    float z = xz[(size_t)(b * L_ + pos) * 512 + 256 + t];
    float sig = 1.f / (1.f + expf(-z));
    yln[(b * L_ + pos) * D_ + t] = ln * z * sig;
}

// ---------------------------------------------------------------------------
// 7a) convert xo (BL,C) f32 -> xob [bh][L][32] bf16
__global__ void k_qbf(const float* __restrict__ xo, short* __restrict__ xob) {
    int row = blockIdx.x * 2 + (threadIdx.x >> 7);
    int col = threadIdx.x & 127;
    int b = row / L_, l = row % L_;
    int h = col >> 5, e = col & 31;
    float v = xo[(size_t)row * C_ + col];
    xob[(((size_t)(b * 4 + h)) * L_ + l) * 32 + e] = f2bf(v);
}

// 7b) MFMA flash attention, q=k=v. grid (L/64, 8 bh, 4 kv-chunks), block 256
__global__ void k_attn_mfma(const short* __restrict__ xob, float* __restrict__ po,
                            float* __restrict__ pm, float* __restrict__ pl) {
    int qt = blockIdx.x, bh = blockIdx.y, ck = blockIdx.z;
    int t = threadIdx.x;
    int wave = t >> 6, lane = t & 63;
    int l15 = lane & 15, quad = lane >> 4;
    __shared__ __attribute__((aligned(16))) short Vt[32][40];  // [e][c] transposed K-tile
    __shared__ __attribute__((aligned(16))) short Ps[4][16][40]; // per-wave P in A-layout
    const short* xb = xob + (size_t)bh * L_ * 32;
    sh8 qf = *(const sh8*)(xb + (size_t)(qt * 64 + wave * 16 + l15) * 32 + quad * 8);
    f4 o0 = {0.f, 0.f, 0.f, 0.f}, o1 = {0.f, 0.f, 0.f, 0.f};
    float mrow[4] = {-1e30f, -1e30f, -1e30f, -1e30f};
    float lrow[4] = {0.f, 0.f, 0.f, 0.f};
    const float scale = 0.17677669529663687f;
    int kt0 = ck * 576;
    for (int kt = kt0; kt < kt0 + 576; kt += 32) {
        __syncthreads();
        {   // stage transposed V tile
            int c = t & 31, e0 = (t >> 5) * 4;
            const short* kp = xb + (size_t)(kt + c) * 32 + e0;
            short4 v = *(const short4*)kp;
            Vt[e0 + 0][c] = v.x;
            Vt[e0 + 1][c] = v.y;
            Vt[e0 + 2][c] = v.z;
            Vt[e0 + 3][c] = v.w;
        }
        __syncthreads();
        const short* kb = xb + (size_t)(kt + l15) * 32 + quad * 8;
        sh8 kf0 = *(const sh8*)kb;
        sh8 kf1 = *(const sh8*)(kb + 16 * 32);
        f4 z4 = {0.f, 0.f, 0.f, 0.f};
        f4 s0 = __builtin_amdgcn_mfma_f32_16x16x32_bf16(qf, kf0, z4, 0, 0, 0);
        f4 s1 = __builtin_amdgcn_mfma_f32_16x16x32_bf16(qf, kf1, z4, 0, 0, 0);
#pragma unroll
        for (int r = 0; r < 4; r++) {
            float a = s0[r] * scale, b2 = s1[r] * scale;
            float rm = fmaxf(a, b2);
            rm = fmaxf(rm, __shfl_xor(rm, 1, 64));
            rm = fmaxf(rm, __shfl_xor(rm, 2, 64));
            rm = fmaxf(rm, __shfl_xor(rm, 4, 64));
            rm = fmaxf(rm, __shfl_xor(rm, 8, 64));
            float mn = fmaxf(mrow[r], rm);
            float al = expf(mrow[r] - mn);
            mrow[r] = mn;
            float pa = expf(a - mn), pb = expf(b2 - mn);
            float rs = pa + pb;
            rs += __shfl_xor(rs, 1, 64);
            rs += __shfl_xor(rs, 2, 64);
            rs += __shfl_xor(rs, 4, 64);
            rs += __shfl_xor(rs, 8, 64);
            lrow[r] = lrow[r] * al + rs;
            o0[r] *= al; o1[r] *= al;
            Ps[wave][quad * 4 + r][l15] = f2bf(pa);
            Ps[wave][quad * 4 + r][l15 + 16] = f2bf(pb);
        }
        sh8 pf = *(const sh8*)&Ps[wave][l15][quad * 8];
        sh8 v0 = *(const sh8*)&Vt[l15][quad * 8];
        sh8 v1 = *(const sh8*)&Vt[l15 + 16][quad * 8];
        o0 = __builtin_amdgcn_mfma_f32_16x16x32_bf16(pf, v0, o0, 0, 0, 0);
        o1 = __builtin_amdgcn_mfma_f32_16x16x32_bf16(pf, v1, o1, 0, 0, 0);
    }
    int qbase = qt * 64 + wave * 16 + quad * 4;
    size_t rb = (size_t)(bh * 4 + ck) * L_;
#pragma unroll
    for (int r = 0; r < 4; r++) {
        po[(rb + qbase + r) * 32 + l15] = o0[r];
        po[(rb + qbase + r) * 32 + l15 + 16] = o1[r];
        if (l15 == 0) { pm[rb + qbase + r] = mrow[r]; pl[rb + qbase + r] = lrow[r]; }
    }
}

// 7c) combine kv-chunk partials -> xo2 (BL,C) f32
__global__ void k_attn_red(const float* __restrict__ po, const float* __restrict__ pm,
                           const float* __restrict__ pl, float* __restrict__ xo2) {
    int t = threadIdx.x;
    int grp = t >> 5, e = t & 31;
    int rowid = blockIdx.x * 8 + grp;
    int bh = rowid / L_, q = rowid % L_;
    size_t rb0 = (size_t)(bh * 4) * L_ + q;
    float mm = -1e30f;
#pragma unroll
    for (int c = 0; c < 4; c++) mm = fmaxf(mm, pm[rb0 + (size_t)c * L_]);
    float lsum = 0.f, acc = 0.f;
#pragma unroll
    for (int c = 0; c < 4; c++) {
        float w = expf(pm[rb0 + (size_t)c * L_] - mm);
        lsum += w * pl[rb0 + (size_t)c * L_];
        acc += w * po[(rb0 + (size_t)c * L_) * 32 + e];
    }
    int b = bh >> 2, h = bh & 3;
    xo2[((size_t)b * L_ + q) * C_ + h * 32 + e] = acc / lsum;
}

// ---------------------------------------------------------------------------
// 10) ghost cheap branch + assemble output + residual
__global__ void k_ghost2(const float* __restrict__ pcl, const float* __restrict__ g2w,
                         const float* __restrict__ g2b, const float* __restrict__ x,
                         float* __restrict__ out) {
    int h = blockIdx.x, b = blockIdx.y;
    __shared__ float tile[3][W_][64];
    int t = threadIdx.x;
    for (int rr = 0; rr < 3; rr++) {
        int hh = h - 1 + rr;
        for (int i = 0; i < 12; i++) {
            int idx = t + i * 256;
            int w = idx >> 6, cc = idx & 63;
            tile[rr][w][cc] = (hh >= 0 && hh < H_) ? pcl[(size_t)(b * L_ + hh * W_ + w) * 64 + cc] : 0.f;
        }
    }
    __syncthreads();
    int cc = t & 63, wg = t >> 6;
    float w9[9];
#pragma unroll
    for (int i = 0; i < 9; i++) w9[i] = g2w[cc * 9 + i];
    float bias = g2b[cc];
    for (int w = wg; w < W_; w += 4) {
        int pos = h * W_ + w;
        float pv = tile[1][w][cc];
        out[(size_t)(b * C_ + cc) * L_ + pos] = pv + x[(size_t)(b * C_ + cc) * L_ + pos];
        float s = bias;
#pragma unroll
        for (int rr = 0; rr < 3; rr++)
#pragma unroll
            for (int c2 = 0; c2 < 3; c2++) {
                int ww = w - 1 + c2;
                if (ww >= 0 && ww < W_) s += tile[rr][ww][cc] * w9[rr * 3 + c2];
            }
        s = fmaxf(s, 0.f);
        out[(size_t)(b * C_ + 64 + cc) * L_ + pos] = s + x[(size_t)(b * C_ + 64 + cc) * L_ + pos];
    }
}

// ---------------------------------------------------------------------------
extern "C" void kernel_launch(void* const* d_in, const int* in_sizes, int n_in,
                              void* d_out, int out_size, void* d_ws, size_t ws_size,
                              hipStream_t stream) {
    const float* x        = (const float*)d_in[0];
    const float* norm_g   = (const float*)d_in[1];
    const float* norm_b   = (const float*)d_in[2];
    const float* in_w     = (const float*)d_in[3];
    const float* in_b     = (const float*)d_in[4];
    const float* conv_w   = (const float*)d_in[5];
    const float* conv_b   = (const float*)d_in[6];
    const float* xpw      = (const float*)d_in[7];
    const float* dtw      = (const float*)d_in[8];
    const float* dtb      = (const float*)d_in[9];
    const float* A_log    = (const float*)d_in[10];
    const float* Ds       = (const float*)d_in[11];
    const float* out_g    = (const float*)d_in[12];
    const float* out_b    = (const float*)d_in[13];
    const float* opw      = (const float*)d_in[14];
    const float* opb      = (const float*)d_in[15];
    const float* g1w      = (const float*)d_in[16];
    const float* g1b      = (const float*)d_in[17];
    const float* g2w      = (const float*)d_in[18];
    const float* g2b      = (const float*)d_in[19];
    float* out = (float*)d_out;

    float* ws = (float*)d_ws;
    size_t off = 0;
    float* xn   = ws + off; off += (size_t)BL_ * C_;          // 589824 (reused as hin)
    float* xz   = ws + off; off += (size_t)BL_ * 2 * D_;      // 2359296
    float* xcl  = ws + off; off += (size_t)BL_ * D_;          // 1179648
    float* dts  = ws + off; off += (size_t)B_ * K_ * L_ * D_; // 4718592 (reused as attn scratch)
    float* Bss  = ws + off; off += (size_t)B_ * K_ * L_ * N_; // 294912 (reused as pcl)
    float* Css  = ws + off; off += (size_t)B_ * K_ * L_ * N_; // 294912
    float* ys   = ws + off; off += (size_t)B_ * K_ * L_ * D_; // 4718592 (P4 aliased at start)
    float* yln  = ws + off; off += (size_t)BL_ * D_;          // 1179648
    float* xo   = ws + off; off += (size_t)BL_ * C_;          // 589824
    float* sumdt= ws + off; off += (size_t)B_ * K_ * S_ * D_; // 131072
    float* hend = ws + off; off += (size_t)B_ * K_ * S_ * D_ * N_; // 524288

    float* hin = xn;            // alias: xn dead after in_proj GEMM
    float* P4  = ys;            // alias: dead before scan pass C writes ys
    // attn scratch aliases dts (dead after scan pass C):
    short* xob = (short*)dts;                         // 1179648 shorts = 589824 f
    float* po  = dts + 589824;                        // 2359296
    float* pmb = po + (size_t)2359296;                // 73728
    float* plb = pmb + 73728;                         // 73728
    float* xo2 = plb + 73728;                         // 589824
    float* pcl = Bss;           // alias: Bss dead after scan pass C

    k_ln<<<dim3(L_ / 16, B_), 256, 0, stream>>>(x, norm_g, norm_b, xn);
    k_gemm<0, true><<<dim3(8, BL_ / 64), 256, 0, stream>>>(xn, in_w, in_b, xz, BL_, 512, C_);
    k_dwconv<<<dim3(D_ / 64, H_, B_), 256, 0, stream>>>(xz, conv_w, conv_b, xcl);
    k_gemm<0, false><<<dim3(3, BL_ / 64), 256, 0, stream>>>(xcl, xpw, nullptr, P4, BL_, 160, D_);
    k_xproj2<<<dim3(L_, K_, B_), 256, 0, stream>>>(P4, dtw, dtb, dts, Bss, Css);
    k_scan_a<<<dim3(D_ / 16, K_ * S_, B_), 256, 0, stream>>>(dts, Bss, xcl, A_log, hend, sumdt);
    k_scan_b<<<dim3(128), 256, 0, stream>>>(hend, sumdt, A_log, hin);
    k_scan_c<<<dim3(D_ / 16, K_ * S_, B_), 256, 0, stream>>>(dts, Bss, Css, xcl, A_log, hin, ys);
    k_combine<<<dim3(BL_), 256, 0, stream>>>(ys, xcl, Ds, xz, out_g, out_b, yln);
    k_gemm<0, true><<<dim3(2, BL_ / 64), 256, 0, stream>>>(yln, opw, opb, xo, BL_, C_, D_);
    k_qbf<<<dim3(BL_ / 2), 256, 0, stream>>>(xo, xob);
    k_attn_mfma<<<dim3(L_ / 64, 8, 4), 256, 0, stream>>>(xob, po, pmb, plb);
    k_attn_red<<<dim3(2304), 256, 0, stream>>>(po, pmb, plb, xo2);
    k_gemm<1, true><<<dim3(1, BL_ / 64), 256, 0, stream>>>(xo2, g1w, g1b, pcl, BL_, 64, C_);
    k_ghost2<<<dim3(H_, B_), 256, 0, stream>>>(pcl, g2w, g2b, x, out);
}

// Round 3
// 306.882 us; speedup vs baseline: 4.7177x; 1.5558x over previous
//
#include <hip/hip_runtime.h>
#include <math.h>

namespace {
constexpr int B_ = 2, C_ = 128, H_ = 48, W_ = 48;
constexpr int L_ = H_ * W_;        // 2304
constexpr int BL_ = B_ * L_;       // 4608
constexpr int D_ = 256, N_ = 16, R_ = 8, K_ = 4;
constexpr int S_ = 64, SEG_ = 36;  // scan segments (S_*SEG_ == L_)
}

typedef __attribute__((ext_vector_type(8))) short sh8;
typedef __attribute__((ext_vector_type(4))) float f4;

__device__ inline short f2bf(float x) {
    unsigned u = __float_as_uint(x);
    unsigned r = (u + 0x7fff + ((u >> 16) & 1)) >> 16;
    return (short)r;
}

// ---------------------------------------------------------------------------
// 0) convert the 4 weight matrices to bf16 (one fused launch)
__global__ void k_tobf4(const float* __restrict__ w0, const float* __restrict__ w1,
                        const float* __restrict__ w2, const float* __restrict__ w3,
                        short* __restrict__ o0, short* __restrict__ o1,
                        short* __restrict__ o2, short* __restrict__ o3) {
    const int n0 = 512 * 128, n1 = 160 * 256, n2 = 128 * 256, n3 = 64 * 128;
    int gid = blockIdx.x * 256 + threadIdx.x;
    if (gid < n0) o0[gid] = f2bf(w0[gid]);
    else if (gid < n0 + n1) o1[gid - n0] = f2bf(w1[gid - n0]);
    else if (gid < n0 + n1 + n2) o2[gid - n0 - n1] = f2bf(w2[gid - n0 - n1]);
    else if (gid < n0 + n1 + n2 + n3) o3[gid - n0 - n1 - n2] = f2bf(w3[gid - n0 - n1 - n2]);
}

// ---------------------------------------------------------------------------
// 1) LayerNorm over channels -> xn bf16 (BL, C)
__global__ void k_ln(const float* __restrict__ x, const float* __restrict__ g,
                     const float* __restrict__ bt, short* __restrict__ xnb) {
    int b = blockIdx.y;
    int pos0 = blockIdx.x * 16;
    __shared__ float tile[C_ * 17];
    int t = threadIdx.x;
    for (int i = 0; i < 8; i++) {
        int idx = t + i * 256;
        int c = idx >> 4, pp = idx & 15;
        tile[c * 17 + pp] = x[(b * C_ + c) * L_ + pos0 + pp];
    }
    __syncthreads();
    int p = t >> 4, lane16 = t & 15;
    float s = 0.f, s2 = 0.f;
#pragma unroll
    for (int i = 0; i < 8; i++) {
        int c = lane16 * 8 + i;
        float v = tile[c * 17 + p];
        s += v; s2 += v * v;
    }
#pragma unroll
    for (int off = 8; off; off >>= 1) {
        s += __shfl_xor(s, off, 64);
        s2 += __shfl_xor(s2, off, 64);
    }
    float mu = s * (1.f / C_);
    float var = s2 * (1.f / C_) - mu * mu;
    float rstd = rsqrtf(var + 1e-6f);
#pragma unroll
    for (int i = 0; i < 8; i++) {
        int c = lane16 * 8 + i;
        float v = tile[c * 17 + p];
        xnb[(b * L_ + pos0 + p) * C_ + c] = f2bf((v - mu) * rstd * g[c] + bt[c]);
    }
}

// ---------------------------------------------------------------------------
// 2) bf16 MFMA GEMM: Cout(M,N) f32 = A(M,K)bf16 * W(N,K)bf16^T (+bias)(+relu)
// grid (ceil(N/64), M/64), block 256 (4 waves, each 16 rows x 64 cols)
template <int ACT, bool BIAS>
__global__ void k_bgemm(const short* __restrict__ A, const short* __restrict__ W,
                        const float* __restrict__ bias, float* __restrict__ Cout,
                        int M, int Nc, int Kc) {
    int n0 = blockIdx.x * 64, m0 = blockIdx.y * 64;
    int t = threadIdx.x, wave = t >> 6, lane = t & 63;
    int l15 = lane & 15, quad = lane >> 4;
    f4 acc[4] = {};
    int mrow = m0 + wave * 16 + l15;
    for (int k0 = 0; k0 < Kc; k0 += 32) {
        sh8 af = *(const sh8*)(A + (size_t)mrow * Kc + k0 + quad * 8);
#pragma unroll
        for (int c = 0; c < 4; c++) {
            int nrow = n0 + c * 16 + l15;
            sh8 bf = {0, 0, 0, 0, 0, 0, 0, 0};
            if (nrow < Nc) bf = *(const sh8*)(W + (size_t)nrow * Kc + k0 + quad * 8);
            acc[c] = __builtin_amdgcn_mfma_f32_16x16x32_bf16(af, bf, acc[c], 0, 0, 0);
        }
    }
#pragma unroll
    for (int c = 0; c < 4; c++) {
        int n = n0 + c * 16 + l15;
        if (n < Nc) {
            float bv = BIAS ? bias[n] : 0.f;
#pragma unroll
            for (int r = 0; r < 4; r++) {
                int m = m0 + wave * 16 + quad * 4 + r;
                float v = acc[c][r] + bv;
                if (ACT == 1) v = fmaxf(v, 0.f);
                Cout[(size_t)m * Nc + n] = v;
            }
        }
    }
}

// ---------------------------------------------------------------------------
// 3) depthwise 3x3 conv + bias + SiLU -> xcl f32 (B,L,D) and xclb bf16
__global__ void k_dwconv(const float* __restrict__ xz, const float* __restrict__ cw,
                         const float* __restrict__ cb, float* __restrict__ xcl,
                         short* __restrict__ xclb) {
    int d0 = blockIdx.x * 64;
    int h = blockIdx.y;
    int b = blockIdx.z;
    __shared__ float tile[3][W_][64];
    int t = threadIdx.x;
    for (int rr = 0; rr < 3; rr++) {
        int hh = h - 1 + rr;
        for (int i = 0; i < 12; i++) {
            int idx = t + i * 256;
            int w = idx >> 6, dd = idx & 63;
            float v = 0.f;
            if (hh >= 0 && hh < H_) v = xz[(size_t)((b * L_ + hh * W_ + w)) * 512 + d0 + dd];
            tile[rr][w][dd] = v;
        }
    }
    __syncthreads();
    int dd = t & 63, wg = t >> 6;
    int d = d0 + dd;
    float w9[9];
#pragma unroll
    for (int i = 0; i < 9; i++) w9[i] = cw[d * 9 + i];
    float bias = cb[d];
    for (int w = wg; w < W_; w += 4) {
        float s = 0.f;
#pragma unroll
        for (int rr = 0; rr < 3; rr++)
#pragma unroll
            for (int c2 = 0; c2 < 3; c2++) {
                int ww = w - 1 + c2;
                float v = (ww >= 0 && ww < W_) ? tile[rr][ww][dd] : 0.f;
                s += v * w9[rr * 3 + c2];
            }
        s += bias;
        float sig = 1.f / (1.f + expf(-s));
        float o = s * sig;
        xcl[(b * L_ + h * W_ + w) * D_ + d] = o;
        xclb[(b * L_ + h * W_ + w) * D_ + d] = f2bf(o);
    }
}

// ---------------------------------------------------------------------------
// 4b) gather P4 (B*L,160) at permuted pos -> dts (softplus), Bs, Cs
__global__ void k_xproj2(const float* __restrict__ P4, const float* __restrict__ dtw,
                         const float* __restrict__ dtb, float* __restrict__ dts,
                         float* __restrict__ Bss, float* __restrict__ Css) {
    int l = blockIdx.x, k = blockIdx.y, b = blockIdx.z;
    int l2 = (k >= 2) ? (L_ - 1 - l) : l;
    int pos = (k & 1) ? ((l2 % H_) * W_ + l2 / H_) : l2;
    __shared__ float xdbl[40];
    int t = threadIdx.x;
    if (t < 40) xdbl[t] = P4[((size_t)(b * L_ + pos)) * 160 + k * 40 + t];
    __syncthreads();
    float s = dtb[k * D_ + t];
    const float* dw = dtw + ((size_t)k * D_ + t) * R_;
#pragma unroll
    for (int r = 0; r < R_; r++) s += xdbl[r] * dw[r];
    float sp = (s > 20.f) ? s : log1pf(expf(s));
    dts[((size_t)(b * K_ + k) * L_ + l) * D_ + t] = sp;
    if (t < N_)
        Bss[((size_t)(b * K_ + k) * L_ + l) * N_ + t] = xdbl[R_ + t];
    else if (t < 2 * N_)
        Css[((size_t)(b * K_ + k) * L_ + l) * N_ + (t - N_)] = xdbl[R_ + N_ + (t - N_)];
}

// ---------------------------------------------------------------------------
// 5a) scan pass A: thread = one d holding all 16 n-states. grid (S, K, B) x 256
__global__ void k_scan_a(const float* __restrict__ dts, const float* __restrict__ Bss,
                         const float* __restrict__ xcl, const float* __restrict__ A_log,
                         float* __restrict__ hend, float* __restrict__ sumdt) {
    int s = blockIdx.x, k = blockIdx.y, b = blockIdx.z;
    int bk = b * K_ + k;
    int d = threadIdx.x;
    int l0 = s * SEG_;
    __shared__ __attribute__((aligned(16))) float sB[SEG_][N_];
    __shared__ int s_pos[SEG_];
    for (int idx = d; idx < SEG_ * N_; idx += 256)
        sB[idx >> 4][idx & 15] = Bss[((size_t)bk * L_ + l0 + (idx >> 4)) * N_ + (idx & 15)];
    if (d < SEG_) {
        int l = l0 + d;
        int l2 = (k >= 2) ? (L_ - 1 - l) : l;
        s_pos[d] = (k & 1) ? ((l2 % H_) * W_ + l2 / H_) : l2;
    }
    float an[N_];
#pragma unroll
    for (int n = 0; n < N_; n++) an[n] = -__expf(A_log[(k * D_ + d) * N_ + n]);
    __syncthreads();
    float h[N_] = {};
    float sd = 0.f;
    const float* dp = dts + ((size_t)bk * L_ + l0) * D_ + d;
    const float* xp = xcl + (size_t)b * L_ * D_ + d;
    float dt_c = dp[0];
    float x_c = xp[(size_t)s_pos[0] * D_];
    for (int ll = 0; ll < SEG_; ll++) {
        int lln = (ll + 1 < SEG_) ? ll + 1 : SEG_ - 1;
        float dt_n = dp[(size_t)lln * D_];
        float x_n = xp[(size_t)s_pos[lln] * D_];
        float dtx = dt_c * x_c;
        sd += dt_c;
        float bb[N_];
        *(float4*)&bb[0]  = *(const float4*)&sB[ll][0];
        *(float4*)&bb[4]  = *(const float4*)&sB[ll][4];
        *(float4*)&bb[8]  = *(const float4*)&sB[ll][8];
        *(float4*)&bb[12] = *(const float4*)&sB[ll][12];
#pragma unroll
        for (int n = 0; n < N_; n++) {
            float a = __expf(dt_c * an[n]);
            h[n] = h[n] * a + dtx * bb[n];
        }
        dt_c = dt_n; x_c = x_n;
    }
    size_t hb = ((size_t)bk * S_ + s) * N_ * D_;
#pragma unroll
    for (int n = 0; n < N_; n++) hend[hb + (size_t)n * D_ + d] = h[n];
    sumdt[((size_t)bk * S_ + s) * D_ + d] = sd;
}

// 5b) cross-segment prefix, in place: hend[s] <- h_in[s]
__global__ void k_scan_b(float* __restrict__ hend, const float* __restrict__ sumdt,
                         const float* __restrict__ A_log) {
    int gid = blockIdx.x * 256 + threadIdx.x;  // 32768
    int d = gid & 255, n = (gid >> 8) & 15, bk = gid >> 12;
    int k = bk & 3;
    float Adn = -__expf(A_log[(k * D_ + d) * N_ + n]);
    float h = 0.f;
    for (int s = 0; s < S_; s++) {
        size_t si = (size_t)bk * S_ + s;
        float P = __expf(Adn * sumdt[si * D_ + d]);
        size_t idx = si * N_ * D_ + (size_t)n * D_ + d;
        float tmp = hend[idx];
        hend[idx] = h;
        h = tmp + P * h;
    }
}

// 5c) scan pass C: replay with h0 = h_in, emit y
__global__ void k_scan_c(const float* __restrict__ dts, const float* __restrict__ Bss,
                         const float* __restrict__ Css, const float* __restrict__ xcl,
                         const float* __restrict__ A_log, const float* __restrict__ hend,
                         float* __restrict__ ys) {
    int s = blockIdx.x, k = blockIdx.y, b = blockIdx.z;
    int bk = b * K_ + k;
    int d = threadIdx.x;
    int l0 = s * SEG_;
    __shared__ __attribute__((aligned(16))) float sB[SEG_][N_];
    __shared__ __attribute__((aligned(16))) float sC[SEG_][N_];
    __shared__ int s_pos[SEG_];
    for (int idx = d; idx < SEG_ * N_; idx += 256) {
        sB[idx >> 4][idx & 15] = Bss[((size_t)bk * L_ + l0 + (idx >> 4)) * N_ + (idx & 15)];
        sC[idx >> 4][idx & 15] = Css[((size_t)bk * L_ + l0 + (idx >> 4)) * N_ + (idx & 15)];
    }
    if (d < SEG_) {
        int l = l0 + d;
        int l2 = (k >= 2) ? (L_ - 1 - l) : l;
        s_pos[d] = (k & 1) ? ((l2 % H_) * W_ + l2 / H_) : l2;
    }
    float an[N_];
#pragma unroll
    for (int n = 0; n < N_; n++) an[n] = -__expf(A_log[(k * D_ + d) * N_ + n]);
    __syncthreads();
    float h[N_];
    size_t hb = ((size_t)bk * S_ + s) * N_ * D_;
#pragma unroll
    for (int n = 0; n < N_; n++) h[n] = hend[hb + (size_t)n * D_ + d];
    const float* dp = dts + ((size_t)bk * L_ + l0) * D_ + d;
    const float* xp = xcl + (size_t)b * L_ * D_ + d;
    float* yp = ys + ((size_t)bk * L_ + l0) * D_ + d;
    float dt_c = dp[0];
    float x_c = xp[(size_t)s_pos[0] * D_];
    for (int ll = 0; ll < SEG_; ll++) {
        int lln = (ll + 1 < SEG_) ? ll + 1 : SEG_ - 1;
        float dt_n = dp[(size_t)lln * D_];
        float x_n = xp[(size_t)s_pos[lln] * D_];
        float dtx = dt_c * x_c;
        float bb[N_], cc[N_];
        *(float4*)&bb[0]  = *(const float4*)&sB[ll][0];
        *(float4*)&bb[4]  = *(const float4*)&sB[ll][4];
        *(float4*)&bb[8]  = *(const float4*)&sB[ll][8];
        *(float4*)&bb[12] = *(const float4*)&sB[ll][12];
        *(float4*)&cc[0]  = *(const float4*)&sC[ll][0];
        *(float4*)&cc[4]  = *(const float4*)&sC[ll][4];
        *(float4*)&cc[8]  = *(const float4*)&sC[ll][8];
        *(float4*)&cc[12] = *(const float4*)&sC[ll][12];
        float y = 0.f;
#pragma unroll
        for (int n = 0; n < N_; n++) {
            float a = __expf(dt_c * an[n]);
            h[n] = h[n] * a + dtx * bb[n];
            y += h[n] * cc[n];
        }
        yp[(size_t)ll * D_] = y;
        dt_c = dt_n; x_c = x_n;
    }
}

// ---------------------------------------------------------------------------
// 6) combine 4 directions + D*x + out-LN + silu(z) gate -> ylnb bf16 (BL,D)
__global__ void k_combine(const float* __restrict__ ys, const float* __restrict__ xcl,
                          const float* __restrict__ Ds, const float* __restrict__ xz,
                          const float* __restrict__ g, const float* __restrict__ bt,
                          short* __restrict__ ylnb) {
    int bp = blockIdx.x;
    int b = bp / L_, pos = bp % L_;
    int t = threadIdx.x;
    int hh = pos / W_, ww = pos % W_;
    int l0 = pos;
    int l1 = ww * H_ + hh;
    int l2 = L_ - 1 - pos;
    int l3 = L_ - 1 - l1;
    size_t base = (size_t)b * K_ * L_ * D_;
    float v = ys[base + ((size_t)0 * L_ + l0) * D_ + t]
            + ys[base + ((size_t)1 * L_ + l1) * D_ + t]
            + ys[base + ((size_t)2 * L_ + l2) * D_ + t]
            + ys[base + ((size_t)3 * L_ + l3) * D_ + t];
    float dsum = Ds[0 * D_ + t] + Ds[1 * D_ + t] + Ds[2 * D_ + t] + Ds[3 * D_ + t];
    v += dsum * xcl[(b * L_ + pos) * D_ + t];

    __shared__ float red[8];
    float s = v, s2 = v * v;
#pragma unroll
    for (int off = 32; off; off >>= 1) {
        s += __shfl_xor(s, off, 64);
        s2 += __shfl_xor(s2, off, 64);
    }
    int wv = t >> 6;
    if ((t & 63) == 0) { red[wv] = s; red[4 + wv] = s2; }
    __syncthreads();
    s = red[0] + red[1] + red[2] + red[3];
    s2 = red[4] + red[5] + red[6] + red[7];
    float mu = s * (1.f / D_);
    float var = s2 * (1.f / D_) - mu * mu;
    float rstd = rsqrtf(var + 1e-6f);
    float ln = (v - mu) * rstd * g[t] + bt[t];
    float z = xz[(size_t)(b * L_ + pos) * 512 + 256 + t];
    float sig = 1.f / (1.f + expf(-z));
    ylnb[(b * L_ + pos) * D_ + t] = f2bf(ln * z * sig);
}

// ---------------------------------------------------------------------------
// 7a) convert xo (BL,C) f32 -> xob [bh][L][32] bf16
__global__ void k_qbf(const float* __restrict__ xo, short* __restrict__ xob) {
    int row = blockIdx.x * 2 + (threadIdx.x >> 7);
    int col = threadIdx.x & 127;
    int b = row / L_, l = row % L_;
    int h = col >> 5, e = col & 31;
    float v = xo[(size_t)row * C_ + col];
    xob[(((size_t)(b * 4 + h)) * L_ + l) * 32 + e] = f2bf(v);
}

// 7b) MFMA flash attention, q=k=v. grid (L/64, 8 bh, 4 kv-chunks), block 256
__global__ void k_attn_mfma(const short* __restrict__ xob, float* __restrict__ po,
                            float* __restrict__ pm, float* __restrict__ pl) {
    int qt = blockIdx.x, bh = blockIdx.y, ck = blockIdx.z;
    int t = threadIdx.x;
    int wave = t >> 6, lane = t & 63;
    int l15 = lane & 15, quad = lane >> 4;
    __shared__ __attribute__((aligned(16))) short Vt[32][40];
    __shared__ __attribute__((aligned(16))) short Ps[4][16][40];
    const short* xb = xob + (size_t)bh * L_ * 32;
    sh8 qf = *(const sh8*)(xb + (size_t)(qt * 64 + wave * 16 + l15) * 32 + quad * 8);
    f4 o0 = {0.f, 0.f, 0.f, 0.f}, o1 = {0.f, 0.f, 0.f, 0.f};
    float mrow[4] = {-1e30f, -1e30f, -1e30f, -1e30f};
    float lrow[4] = {0.f, 0.f, 0.f, 0.f};
    const float scale = 0.17677669529663687f;
    int kt0 = ck * 576;
    for (int kt = kt0; kt < kt0 + 576; kt += 32) {
        __syncthreads();
        {
            int c = t & 31, e0 = (t >> 5) * 4;
            const short* kp = xb + (size_t)(kt + c) * 32 + e0;
            short4 v = *(const short4*)kp;
            Vt[e0 + 0][c] = v.x;
            Vt[e0 + 1][c] = v.y;
            Vt[e0 + 2][c] = v.z;
            Vt[e0 + 3][c] = v.w;
        }
        __syncthreads();
        const short* kb = xb + (size_t)(kt + l15) * 32 + quad * 8;
        sh8 kf0 = *(const sh8*)kb;
        sh8 kf1 = *(const sh8*)(kb + 16 * 32);
        f4 z4 = {0.f, 0.f, 0.f, 0.f};
        f4 s0 = __builtin_amdgcn_mfma_f32_16x16x32_bf16(qf, kf0, z4, 0, 0, 0);
        f4 s1 = __builtin_amdgcn_mfma_f32_16x16x32_bf16(qf, kf1, z4, 0, 0, 0);
#pragma unroll
        for (int r = 0; r < 4; r++) {
            float a = s0[r] * scale, b2 = s1[r] * scale;
            float rm = fmaxf(a, b2);
            rm = fmaxf(rm, __shfl_xor(rm, 1, 64));
            rm = fmaxf(rm, __shfl_xor(rm, 2, 64));
            rm = fmaxf(rm, __shfl_xor(rm, 4, 64));
            rm = fmaxf(rm, __shfl_xor(rm, 8, 64));
            float mn = fmaxf(mrow[r], rm);
            float al = expf(mrow[r] - mn);
            mrow[r] = mn;
            float pa = expf(a - mn), pb = expf(b2 - mn);
            float rs = pa + pb;
            rs += __shfl_xor(rs, 1, 64);
            rs += __shfl_xor(rs, 2, 64);
            rs += __shfl_xor(rs, 4, 64);
            rs += __shfl_xor(rs, 8, 64);
            lrow[r] = lrow[r] * al + rs;
            o0[r] *= al; o1[r] *= al;
            Ps[wave][quad * 4 + r][l15] = f2bf(pa);
            Ps[wave][quad * 4 + r][l15 + 16] = f2bf(pb);
        }
        sh8 pf = *(const sh8*)&Ps[wave][l15][quad * 8];
        sh8 v0 = *(const sh8*)&Vt[l15][quad * 8];
        sh8 v1 = *(const sh8*)&Vt[l15 + 16][quad * 8];
        o0 = __builtin_amdgcn_mfma_f32_16x16x32_bf16(pf, v0, o0, 0, 0, 0);
        o1 = __builtin_amdgcn_mfma_f32_16x16x32_bf16(pf, v1, o1, 0, 0, 0);
    }
    int qbase = qt * 64 + wave * 16 + quad * 4;
    size_t rb = (size_t)(bh * 4 + ck) * L_;
#pragma unroll
    for (int r = 0; r < 4; r++) {
        po[(rb + qbase + r) * 32 + l15] = o0[r];
        po[(rb + qbase + r) * 32 + l15 + 16] = o1[r];
        if (l15 == 0) { pm[rb + qbase + r] = mrow[r]; pl[rb + qbase + r] = lrow[r]; }
    }
}

// 7c) combine kv-chunk partials -> xo2b bf16 (BL,C)
__global__ void k_attn_red(const float* __restrict__ po, const float* __restrict__ pm,
                           const float* __restrict__ pl, short* __restrict__ xo2b) {
    int t = threadIdx.x;
    int grp = t >> 5, e = t & 31;
    int rowid = blockIdx.x * 8 + grp;
    int bh = rowid / L_, q = rowid % L_;
    size_t rb0 = (size_t)(bh * 4) * L_ + q;
    float mm = -1e30f;
#pragma unroll
    for (int c = 0; c < 4; c++) mm = fmaxf(mm, pm[rb0 + (size_t)c * L_]);
    float lsum = 0.f, acc = 0.f;
#pragma unroll
    for (int c = 0; c < 4; c++) {
        float w = expf(pm[rb0 + (size_t)c * L_] - mm);
        lsum += w * pl[rb0 + (size_t)c * L_];
        acc += w * po[(rb0 + (size_t)c * L_) * 32 + e];
    }
    int b = bh >> 2, h = bh & 3;
    xo2b[((size_t)b * L_ + q) * C_ + h * 32 + e] = f2bf(acc / lsum);
}

// ---------------------------------------------------------------------------
// 10) ghost cheap branch + assemble output + residual
__global__ void k_ghost2(const float* __restrict__ pcl, const float* __restrict__ g2w,
                         const float* __restrict__ g2b, const float* __restrict__ x,
                         float* __restrict__ out) {
    int h = blockIdx.x, b = blockIdx.y;
    __shared__ float tile[3][W_][64];
    int t = threadIdx.x;
    for (int rr = 0; rr < 3; rr++) {
        int hh = h - 1 + rr;
        for (int i = 0; i < 12; i++) {
            int idx = t + i * 256;
            int w = idx >> 6, cc = idx & 63;
            tile[rr][w][cc] = (hh >= 0 && hh < H_) ? pcl[(size_t)(b * L_ + hh * W_ + w) * 64 + cc] : 0.f;
        }
    }
    __syncthreads();
    int cc = t & 63, wg = t >> 6;
    float w9[9];
#pragma unroll
    for (int i = 0; i < 9; i++) w9[i] = g2w[cc * 9 + i];
    float bias = g2b[cc];
    for (int w = wg; w < W_; w += 4) {
        int pos = h * W_ + w;
        float pv = tile[1][w][cc];
        out[(size_t)(b * C_ + cc) * L_ + pos] = pv + x[(size_t)(b * C_ + cc) * L_ + pos];
        float s = bias;
#pragma unroll
        for (int rr = 0; rr < 3; rr++)
#pragma unroll
            for (int c2 = 0; c2 < 3; c2++) {
                int ww = w - 1 + c2;
                if (ww >= 0 && ww < W_) s += tile[rr][ww][cc] * w9[rr * 3 + c2];
            }
        s = fmaxf(s, 0.f);
        out[(size_t)(b * C_ + 64 + cc) * L_ + pos] = s + x[(size_t)(b * C_ + 64 + cc) * L_ + pos];
    }
}

// ---------------------------------------------------------------------------
extern "C" void kernel_launch(void* const* d_in, const int* in_sizes, int n_in,
                              void* d_out, int out_size, void* d_ws, size_t ws_size,
                              hipStream_t stream) {
    const float* x        = (const float*)d_in[0];
    const float* norm_g   = (const float*)d_in[1];
    const float* norm_b   = (const float*)d_in[2];
    const float* in_w     = (const float*)d_in[3];
    const float* in_b     = (const float*)d_in[4];
    const float* conv_w   = (const float*)d_in[5];
    const float* conv_b   = (const float*)d_in[6];
    const float* xpw      = (const float*)d_in[7];
    const float* dtw      = (const float*)d_in[8];
    const float* dtb      = (const float*)d_in[9];
    const float* A_log    = (const float*)d_in[10];
    const float* Ds       = (const float*)d_in[11];
    const float* out_g    = (const float*)d_in[12];
    const float* out_b    = (const float*)d_in[13];
    const float* opw      = (const float*)d_in[14];
    const float* opb      = (const float*)d_in[15];
    const float* g1w      = (const float*)d_in[16];
    const float* g1b      = (const float*)d_in[17];
    const float* g2w      = (const float*)d_in[18];
    const float* g2b      = (const float*)d_in[19];
    float* out = (float*)d_out;

    float* ws = (float*)d_ws;
    size_t off = 0;
    float* xz    = ws + off; off += (size_t)BL_ * 2 * D_;      // 2359296
    float* xcl   = ws + off; off += (size_t)BL_ * D_;          // 1179648
    float* dts   = ws + off; off += (size_t)B_ * K_ * L_ * D_; // 4718592 (attn scratch alias)
    float* Bss   = ws + off; off += (size_t)B_ * K_ * L_ * N_; // 294912 (pcl alias)
    float* Css   = ws + off; off += (size_t)B_ * K_ * L_ * N_; // 294912
    float* ys    = ws + off; off += (size_t)B_ * K_ * L_ * D_; // 4718592 (P4 alias)
    float* xo    = ws + off; off += (size_t)BL_ * C_;          // 589824
    float* hend  = ws + off; off += (size_t)B_ * K_ * S_ * D_ * N_; // 8388608
    float* sumdt = ws + off; off += (size_t)B_ * K_ * S_ * D_; // 131072
    short* xnb   = (short*)(ws + off); off += (size_t)BL_ * C_ / 2;      // bf16 xn
    short* xclb  = (short*)(ws + off); off += (size_t)BL_ * D_ / 2;      // bf16 xcl
    short* ylnb  = (short*)(ws + off); off += (size_t)BL_ * D_ / 2;      // bf16 yln
    short* xo2b  = (short*)(ws + off); off += (size_t)BL_ * C_ / 2;      // bf16 xo2
    short* wbf   = (short*)(ws + off); off += 147456 / 2;                 // bf16 weights

    short* in_wb = wbf;
    short* xpwb  = wbf + 512 * 128;
    short* opwb  = xpwb + 160 * 256;
    short* g1wb  = opwb + 128 * 256;

    float* P4 = ys;  // alias: dead before scan pass C writes ys
    // attn scratch aliases dts (dead after scan pass C):
    short* xob = (short*)dts;                 // 589824 elems (294912 f-slots)
    float* po  = dts + 294912;                // 2359296
    float* pmb = po + (size_t)2359296;        // 73728
    float* plb = pmb + 73728;                 // 73728
    float* pcl = Bss;  // alias: Bss dead after scan pass C

    k_tobf4<<<dim3(576), 256, 0, stream>>>(in_w, xpw, opw, g1w, in_wb, xpwb, opwb, g1wb);
    k_ln<<<dim3(L_ / 16, B_), 256, 0, stream>>>(x, norm_g, norm_b, xnb);
    k_bgemm<0, true><<<dim3(8, BL_ / 64), 256, 0, stream>>>(xnb, in_wb, in_b, xz, BL_, 512, C_);
    k_dwconv<<<dim3(D_ / 64, H_, B_), 256, 0, stream>>>(xz, conv_w, conv_b, xcl, xclb);
    k_bgemm<0, false><<<dim3(3, BL_ / 64), 256, 0, stream>>>(xclb, xpwb, nullptr, P4, BL_, 160, D_);
    k_xproj2<<<dim3(L_, K_, B_), 256, 0, stream>>>(P4, dtw, dtb, dts, Bss, Css);
    k_scan_a<<<dim3(S_, K_, B_), 256, 0, stream>>>(dts, Bss, xcl, A_log, hend, sumdt);
    k_scan_b<<<dim3(128), 256, 0, stream>>>(hend, sumdt, A_log);
    k_scan_c<<<dim3(S_, K_, B_), 256, 0, stream>>>(dts, Bss, Css, xcl, A_log, hend, ys);
    k_combine<<<dim3(BL_), 256, 0, stream>>>(ys, xcl, Ds, xz, out_g, out_b, ylnb);
    k_bgemm<0, true><<<dim3(2, BL_ / 64), 256, 0, stream>>>(ylnb, opwb, opb, xo, BL_, C_, D_);
    k_qbf<<<dim3(BL_ / 2), 256, 0, stream>>>(xo, xob);
    k_attn_mfma<<<dim3(L_ / 64, 8, 4), 256, 0, stream>>>(xob, po, pmb, plb);
    k_attn_red<<<dim3(2304), 256, 0, stream>>>(po, pmb, plb, xo2b);
    k_bgemm<1, true><<<dim3(1, BL_ / 64), 256, 0, stream>>>(xo2b, g1wb, g1b, pcl, BL_, 64, C_);
    k_ghost2<<<dim3(H_, B_), 256, 0, stream>>>(pcl, g2w, g2b, x, out);
}

// Round 7
// 295.997 us; speedup vs baseline: 4.8912x; 1.0368x over previous
//
#include <hip/hip_runtime.h>
#include <math.h>

namespace {
constexpr int B_ = 2, C_ = 128, H_ = 48, W_ = 48;
constexpr int L_ = H_ * W_;        // 2304
constexpr int BL_ = B_ * L_;       // 4608
constexpr int D_ = 256, N_ = 16, R_ = 8, K_ = 4;
constexpr int S_ = 64, SEG_ = 36;  // scan segments (S_*SEG_ == L_)
constexpr int CK_ = 8, CHL_ = L_ / CK_;  // attention kv-chunks (288 each)
}

typedef __attribute__((ext_vector_type(8))) short sh8;
typedef __attribute__((ext_vector_type(4))) float f4;

__device__ inline short f2bf(float x) {
    unsigned u = __float_as_uint(x);
    unsigned r = (u + 0x7fff + ((u >> 16) & 1)) >> 16;
    return (short)r;
}

// ---------------------------------------------------------------------------
// 0) convert the 4 weight matrices to bf16 (one fused launch)
__global__ void k_tobf4(const float* __restrict__ w0, const float* __restrict__ w1,
                        const float* __restrict__ w2, const float* __restrict__ w3,
                        short* __restrict__ o0, short* __restrict__ o1,
                        short* __restrict__ o2, short* __restrict__ o3) {
    const int n0 = 512 * 128, n1 = 160 * 256, n2 = 128 * 256, n3 = 64 * 128;
    int gid = blockIdx.x * 256 + threadIdx.x;
    if (gid < n0) o0[gid] = f2bf(w0[gid]);
    else if (gid < n0 + n1) o1[gid - n0] = f2bf(w1[gid - n0]);
    else if (gid < n0 + n1 + n2) o2[gid - n0 - n1] = f2bf(w2[gid - n0 - n1]);
    else if (gid < n0 + n1 + n2 + n3) o3[gid - n0 - n1 - n2] = f2bf(w3[gid - n0 - n1 - n2]);
}

// ---------------------------------------------------------------------------
// 1) LayerNorm over channels -> xn bf16 (BL, C)
__global__ void k_ln(const float* __restrict__ x, const float* __restrict__ g,
                     const float* __restrict__ bt, short* __restrict__ xnb) {
    int b = blockIdx.y;
    int pos0 = blockIdx.x * 16;
    __shared__ float tile[C_ * 17];
    int t = threadIdx.x;
    for (int i = 0; i < 8; i++) {
        int idx = t + i * 256;
        int c = idx >> 4, pp = idx & 15;
        tile[c * 17 + pp] = x[(b * C_ + c) * L_ + pos0 + pp];
    }
    __syncthreads();
    int p = t >> 4, lane16 = t & 15;
    float s = 0.f, s2 = 0.f;
#pragma unroll
    for (int i = 0; i < 8; i++) {
        int c = lane16 * 8 + i;
        float v = tile[c * 17 + p];
        s += v; s2 += v * v;
    }
#pragma unroll
    for (int off = 8; off; off >>= 1) {
        s += __shfl_xor(s, off, 64);
        s2 += __shfl_xor(s2, off, 64);
    }
    float mu = s * (1.f / C_);
    float var = s2 * (1.f / C_) - mu * mu;
    float rstd = rsqrtf(var + 1e-6f);
#pragma unroll
    for (int i = 0; i < 8; i++) {
        int c = lane16 * 8 + i;
        float v = tile[c * 17 + p];
        xnb[(b * L_ + pos0 + p) * C_ + c] = f2bf((v - mu) * rstd * g[c] + bt[c]);
    }
}

// ---------------------------------------------------------------------------
// 2) bf16 MFMA GEMM: Cout(M,N) f32 = A(M,K)bf16 * W(N,K)bf16^T (+bias)(+relu)
template <int ACT, bool BIAS>
__global__ void k_bgemm(const short* __restrict__ A, const short* __restrict__ W,
                        const float* __restrict__ bias, float* __restrict__ Cout,
                        int M, int Nc, int Kc) {
    int n0 = blockIdx.x * 64, m0 = blockIdx.y * 64;
    int t = threadIdx.x, wave = t >> 6, lane = t & 63;
    int l15 = lane & 15, quad = lane >> 4;
    f4 acc[4] = {};
    int mrow = m0 + wave * 16 + l15;
    for (int k0 = 0; k0 < Kc; k0 += 32) {
        sh8 af = *(const sh8*)(A + (size_t)mrow * Kc + k0 + quad * 8);
#pragma unroll
        for (int c = 0; c < 4; c++) {
            int nrow = n0 + c * 16 + l15;
            sh8 bf = {0, 0, 0, 0, 0, 0, 0, 0};
            if (nrow < Nc) bf = *(const sh8*)(W + (size_t)nrow * Kc + k0 + quad * 8);
            acc[c] = __builtin_amdgcn_mfma_f32_16x16x32_bf16(af, bf, acc[c], 0, 0, 0);
        }
    }
#pragma unroll
    for (int c = 0; c < 4; c++) {
        int n = n0 + c * 16 + l15;
        if (n < Nc) {
            float bv = BIAS ? bias[n] : 0.f;
#pragma unroll
            for (int r = 0; r < 4; r++) {
                int m = m0 + wave * 16 + quad * 4 + r;
                float v = acc[c][r] + bv;
                if (ACT == 1) v = fmaxf(v, 0.f);
                Cout[(size_t)m * Nc + n] = v;
            }
        }
    }
}

// ---------------------------------------------------------------------------
// 3) depthwise 3x3 conv + bias + SiLU -> xcl f32 (B,L,D) and xclb bf16
__global__ void k_dwconv(const float* __restrict__ xz, const float* __restrict__ cw,
                         const float* __restrict__ cb, float* __restrict__ xcl,
                         short* __restrict__ xclb) {
    int d0 = blockIdx.x * 64;
    int h = blockIdx.y;
    int b = blockIdx.z;
    __shared__ float tile[3][W_][64];
    int t = threadIdx.x;
    for (int rr = 0; rr < 3; rr++) {
        int hh = h - 1 + rr;
        for (int i = 0; i < 12; i++) {
            int idx = t + i * 256;
            int w = idx >> 6, dd = idx & 63;
            float v = 0.f;
            if (hh >= 0 && hh < H_) v = xz[(size_t)((b * L_ + hh * W_ + w)) * 512 + d0 + dd];
            tile[rr][w][dd] = v;
        }
    }
    __syncthreads();
    int dd = t & 63, wg = t >> 6;
    int d = d0 + dd;
    float w9[9];
#pragma unroll
    for (int i = 0; i < 9; i++) w9[i] = cw[d * 9 + i];
    float bias = cb[d];
    for (int w = wg; w < W_; w += 4) {
        float s = 0.f;
#pragma unroll
        for (int rr = 0; rr < 3; rr++)
#pragma unroll
            for (int c2 = 0; c2 < 3; c2++) {
                int ww = w - 1 + c2;
                float v = (ww >= 0 && ww < W_) ? tile[rr][ww][dd] : 0.f;
                s += v * w9[rr * 3 + c2];
            }
        s += bias;
        float sig = 1.f / (1.f + expf(-s));
        float o = s * sig;
        xcl[(b * L_ + h * W_ + w) * D_ + d] = o;
        xclb[(b * L_ + h * W_ + w) * D_ + d] = f2bf(o);
    }
}

// ---------------------------------------------------------------------------
// 4b) gather P4 (B*L,160) at permuted pos -> dts (softplus), Bs, Cs
__global__ void k_xproj2(const float* __restrict__ P4, const float* __restrict__ dtw,
                         const float* __restrict__ dtb, float* __restrict__ dts,
                         float* __restrict__ Bss, float* __restrict__ Css) {
    int l = blockIdx.x, k = blockIdx.y, b = blockIdx.z;
    int l2 = (k >= 2) ? (L_ - 1 - l) : l;
    int pos = (k & 1) ? ((l2 % H_) * W_ + l2 / H_) : l2;
    __shared__ float xdbl[40];
    int t = threadIdx.x;
    if (t < 40) xdbl[t] = P4[((size_t)(b * L_ + pos)) * 160 + k * 40 + t];
    __syncthreads();
    float s = dtb[k * D_ + t];
    const float* dw = dtw + ((size_t)k * D_ + t) * R_;
#pragma unroll
    for (int r = 0; r < R_; r++) s += xdbl[r] * dw[r];
    float sp = (s > 20.f) ? s : log1pf(expf(s));
    dts[((size_t)(b * K_ + k) * L_ + l) * D_ + t] = sp;
    if (t < N_)
        Bss[((size_t)(b * K_ + k) * L_ + l) * N_ + t] = xdbl[R_ + t];
    else if (t < 2 * N_)
        Css[((size_t)(b * K_ + k) * L_ + l) * N_ + (t - N_)] = xdbl[R_ + N_ + (t - N_)];
}

// ---------------------------------------------------------------------------
// 5a) scan pass A
__global__ void k_scan_a(const float* __restrict__ dts, const float* __restrict__ Bss,
                         const float* __restrict__ xcl, const float* __restrict__ A_log,
                         float* __restrict__ hend, float* __restrict__ sumdt) {
    int s = blockIdx.x, k = blockIdx.y, b = blockIdx.z;
    int bk = b * K_ + k;
    int d = threadIdx.x;
    int l0 = s * SEG_;
    __shared__ __attribute__((aligned(16))) float sB[SEG_][N_];
    __shared__ int s_pos[SEG_];
    for (int idx = d; idx < SEG_ * N_; idx += 256)
        sB[idx >> 4][idx & 15] = Bss[((size_t)bk * L_ + l0 + (idx >> 4)) * N_ + (idx & 15)];
    if (d < SEG_) {
        int l = l0 + d;
        int l2 = (k >= 2) ? (L_ - 1 - l) : l;
        s_pos[d] = (k & 1) ? ((l2 % H_) * W_ + l2 / H_) : l2;
    }
    float an[N_];
#pragma unroll
    for (int n = 0; n < N_; n++) an[n] = -__expf(A_log[(k * D_ + d) * N_ + n]);
    __syncthreads();
    float h[N_] = {};
    float sd = 0.f;
    const float* dp = dts + ((size_t)bk * L_ + l0) * D_ + d;
    const float* xp = xcl + (size_t)b * L_ * D_ + d;
    float dt_c = dp[0];
    float x_c = xp[(size_t)s_pos[0] * D_];
    for (int ll = 0; ll < SEG_; ll++) {
        int lln = (ll + 1 < SEG_) ? ll + 1 : SEG_ - 1;
        float dt_n = dp[(size_t)lln * D_];
        float x_n = xp[(size_t)s_pos[lln] * D_];
        float dtx = dt_c * x_c;
        sd += dt_c;
        float bb[N_];
        *(float4*)&bb[0]  = *(const float4*)&sB[ll][0];
        *(float4*)&bb[4]  = *(const float4*)&sB[ll][4];
        *(float4*)&bb[8]  = *(const float4*)&sB[ll][8];
        *(float4*)&bb[12] = *(const float4*)&sB[ll][12];
#pragma unroll
        for (int n = 0; n < N_; n++) {
            float a = __expf(dt_c * an[n]);
            h[n] = h[n] * a + dtx * bb[n];
        }
        dt_c = dt_n; x_c = x_n;
    }
    size_t hb = ((size_t)bk * S_ + s) * N_ * D_;
#pragma unroll
    for (int n = 0; n < N_; n++) hend[hb + (size_t)n * D_ + d] = h[n];
    sumdt[((size_t)bk * S_ + s) * D_ + d] = sd;
}

// 5b) cross-segment prefix, in place
__global__ void k_scan_b(float* __restrict__ hend, const float* __restrict__ sumdt,
                         const float* __restrict__ A_log) {
    int gid = blockIdx.x * 256 + threadIdx.x;  // 32768
    int d = gid & 255, n = (gid >> 8) & 15, bk = gid >> 12;
    int k = bk & 3;
    float Adn = -__expf(A_log[(k * D_ + d) * N_ + n]);
    float h = 0.f;
    for (int s = 0; s < S_; s++) {
        size_t si = (size_t)bk * S_ + s;
        float P = __expf(Adn * sumdt[si * D_ + d]);
        size_t idx = si * N_ * D_ + (size_t)n * D_ + d;
        float tmp = hend[idx];
        hend[idx] = h;
        h = tmp + P * h;
    }
}

// 5c) scan pass C
__global__ void k_scan_c(const float* __restrict__ dts, const float* __restrict__ Bss,
                         const float* __restrict__ Css, const float* __restrict__ xcl,
                         const float* __restrict__ A_log, const float* __restrict__ hend,
                         float* __restrict__ ys) {
    int s = blockIdx.x, k = blockIdx.y, b = blockIdx.z;
    int bk = b * K_ + k;
    int d = threadIdx.x;
    int l0 = s * SEG_;
    __shared__ __attribute__((aligned(16))) float sB[SEG_][N_];
    __shared__ __attribute__((aligned(16))) float sC[SEG_][N_];
    __shared__ int s_pos[SEG_];
    for (int idx = d; idx < SEG_ * N_; idx += 256) {
        sB[idx >> 4][idx & 15] = Bss[((size_t)bk * L_ + l0 + (idx >> 4)) * N_ + (idx & 15)];
        sC[idx >> 4][idx & 15] = Css[((size_t)bk * L_ + l0 + (idx >> 4)) * N_ + (idx & 15)];
    }
    if (d < SEG_) {
        int l = l0 + d;
        int l2 = (k >= 2) ? (L_ - 1 - l) : l;
        s_pos[d] = (k & 1) ? ((l2 % H_) * W_ + l2 / H_) : l2;
    }
    float an[N_];
#pragma unroll
    for (int n = 0; n < N_; n++) an[n] = -__expf(A_log[(k * D_ + d) * N_ + n]);
    __syncthreads();
    float h[N_];
    size_t hb = ((size_t)bk * S_ + s) * N_ * D_;
#pragma unroll
    for (int n = 0; n < N_; n++) h[n] = hend[hb + (size_t)n * D_ + d];
    const float* dp = dts + ((size_t)bk * L_ + l0) * D_ + d;
    const float* xp = xcl + (size_t)b * L_ * D_ + d;
    float* yp = ys + ((size_t)bk * L_ + l0) * D_ + d;
    float dt_c = dp[0];
    float x_c = xp[(size_t)s_pos[0] * D_];
    for (int ll = 0; ll < SEG_; ll++) {
        int lln = (ll + 1 < SEG_) ? ll + 1 : SEG_ - 1;
        float dt_n = dp[(size_t)lln * D_];
        float x_n = xp[(size_t)s_pos[lln] * D_];
        float dtx = dt_c * x_c;
        float bb[N_], cc[N_];
        *(float4*)&bb[0]  = *(const float4*)&sB[ll][0];
        *(float4*)&bb[4]  = *(const float4*)&sB[ll][4];
        *(float4*)&bb[8]  = *(const float4*)&sB[ll][8];
        *(float4*)&bb[12] = *(const float4*)&sB[ll][12];
        *(float4*)&cc[0]  = *(const float4*)&sC[ll][0];
        *(float4*)&cc[4]  = *(const float4*)&sC[ll][4];
        *(float4*)&cc[8]  = *(const float4*)&sC[ll][8];
        *(float4*)&cc[12] = *(const float4*)&sC[ll][12];
        float y = 0.f;
#pragma unroll
        for (int n = 0; n < N_; n++) {
            float a = __expf(dt_c * an[n]);
            h[n] = h[n] * a + dtx * bb[n];
            y += h[n] * cc[n];
        }
        yp[(size_t)ll * D_] = y;
        dt_c = dt_n; x_c = x_n;
    }
}

// ---------------------------------------------------------------------------
// 6) combine 4 directions + D*x + out-LN + silu(z) gate -> ylnb bf16 (BL,D)
__global__ void k_combine(const float* __restrict__ ys, const float* __restrict__ xcl,
                          const float* __restrict__ Ds, const float* __restrict__ xz,
                          const float* __restrict__ g, const float* __restrict__ bt,
                          short* __restrict__ ylnb) {
    int bp = blockIdx.x;
    int b = bp / L_, pos = bp % L_;
    int t = threadIdx.x;
    int hh = pos / W_, ww = pos % W_;
    int l0 = pos;
    int l1 = ww * H_ + hh;
    int l2 = L_ - 1 - pos;
    int l3 = L_ - 1 - l1;
    size_t base = (size_t)b * K_ * L_ * D_;
    float v = ys[base + ((size_t)0 * L_ + l0) * D_ + t]
            + ys[base + ((size_t)1 * L_ + l1) * D_ + t]
            + ys[base + ((size_t)2 * L_ + l2) * D_ + t]
            + ys[base + ((size_t)3 * L_ + l3) * D_ + t];
    float dsum = Ds[0 * D_ + t] + Ds[1 * D_ + t] + Ds[2 * D_ + t] + Ds[3 * D_ + t];
    v += dsum * xcl[(b * L_ + pos) * D_ + t];

    __shared__ float red[8];
    float s = v, s2 = v * v;
#pragma unroll
    for (int off = 32; off; off >>= 1) {
        s += __shfl_xor(s, off, 64);
        s2 += __shfl_xor(s2, off, 64);
    }
    int wv = t >> 6;
    if ((t & 63) == 0) { red[wv] = s; red[4 + wv] = s2; }
    __syncthreads();
    s = red[0] + red[1] + red[2] + red[3];
    s2 = red[4] + red[5] + red[6] + red[7];
    float mu = s * (1.f / D_);
    float var = s2 * (1.f / D_) - mu * mu;
    float rstd = rsqrtf(var + 1e-6f);
    float ln = (v - mu) * rstd * g[t] + bt[t];
    float z = xz[(size_t)(b * L_ + pos) * 512 + 256 + t];
    float sig = 1.f / (1.f + expf(-z));
    ylnb[(b * L_ + pos) * D_ + t] = f2bf(ln * z * sig);
}

// ---------------------------------------------------------------------------
// 7a) convert xo (BL,C) f32 -> xob [bh][L][32] bf16
__global__ void k_qbf(const float* __restrict__ xo, short* __restrict__ xob) {
    int row = blockIdx.x * 2 + (threadIdx.x >> 7);
    int col = threadIdx.x & 127;
    int b = row / L_, l = row % L_;
    int h = col >> 5, e = col & 31;
    float v = xo[(size_t)row * C_ + col];
    xob[(((size_t)(b * 4 + h)) * L_ + l) * 32 + e] = f2bf(v);
}

// 7b) MFMA flash attention, q=k=v: online max via shuffles, row-sum via
// ol = P*ones MFMA (alpha-rescaled like o0/o1). grid (36, 8 bh, CK_)
__global__ void k_attn_mfma(const short* __restrict__ xob, float* __restrict__ po,
                            float* __restrict__ pm, float* __restrict__ pl) {
    int qt = blockIdx.x, bh = blockIdx.y, ck = blockIdx.z;
    int t = threadIdx.x;
    int wave = t >> 6, lane = t & 63;
    int l15 = lane & 15, quad = lane >> 4;
    __shared__ __attribute__((aligned(16))) short Vt[32][40];
    __shared__ __attribute__((aligned(16))) short Ps[4][16][40];
    const short* xb = xob + (size_t)bh * L_ * 32;
    sh8 qf = *(const sh8*)(xb + (size_t)(qt * 64 + wave * 16 + l15) * 32 + quad * 8);
    f4 o0 = {0.f, 0.f, 0.f, 0.f}, o1 = {0.f, 0.f, 0.f, 0.f}, ol = {0.f, 0.f, 0.f, 0.f};
    float mrow[4] = {-1e30f, -1e30f, -1e30f, -1e30f};
    const float scale = 0.17677669529663687f;
    const short one_bf = (short)0x3F80;
    sh8 ones = {one_bf, one_bf, one_bf, one_bf, one_bf, one_bf, one_bf, one_bf};
    int kt0 = ck * CHL_;
    for (int kt = kt0; kt < kt0 + CHL_; kt += 32) {
        __syncthreads();
        {
            int c = t & 31, e0 = (t >> 5) * 4;
            const short* kp = xb + (size_t)(kt + c) * 32 + e0;
            short4 v = *(const short4*)kp;
            Vt[e0 + 0][c] = v.x;
            Vt[e0 + 1][c] = v.y;
            Vt[e0 + 2][c] = v.z;
            Vt[e0 + 3][c] = v.w;
        }
        __syncthreads();
        const short* kb = xb + (size_t)(kt + l15) * 32 + quad * 8;
        sh8 kf0 = *(const sh8*)kb;
        sh8 kf1 = *(const sh8*)(kb + 16 * 32);
        f4 z4 = {0.f, 0.f, 0.f, 0.f};
        f4 s0 = __builtin_amdgcn_mfma_f32_16x16x32_bf16(qf, kf0, z4, 0, 0, 0);
        f4 s1 = __builtin_amdgcn_mfma_f32_16x16x32_bf16(qf, kf1, z4, 0, 0, 0);
#pragma unroll
        for (int r = 0; r < 4; r++) {
            float a = s0[r] * scale, b2 = s1[r] * scale;
            float rm = fmaxf(a, b2);
            rm = fmaxf(rm, __shfl_xor(rm, 1, 64));
            rm = fmaxf(rm, __shfl_xor(rm, 2, 64));
            rm = fmaxf(rm, __shfl_xor(rm, 4, 64));
            rm = fmaxf(rm, __shfl_xor(rm, 8, 64));
            float mn = fmaxf(mrow[r], rm);
            float al = expf(mrow[r] - mn);
            mrow[r] = mn;
            float pa = expf(a - mn), pb = expf(b2 - mn);
            o0[r] *= al; o1[r] *= al; ol[r] *= al;
            Ps[wave][quad * 4 + r][l15] = f2bf(pa);
            Ps[wave][quad * 4 + r][l15 + 16] = f2bf(pb);
        }
        sh8 pf = *(const sh8*)&Ps[wave][l15][quad * 8];
        sh8 v0 = *(const sh8*)&Vt[l15][quad * 8];
        sh8 v1 = *(const sh8*)&Vt[l15 + 16][quad * 8];
        o0 = __builtin_amdgcn_mfma_f32_16x16x32_bf16(pf, v0, o0, 0, 0, 0);
        o1 = __builtin_amdgcn_mfma_f32_16x16x32_bf16(pf, v1, o1, 0, 0, 0);
        ol = __builtin_amdgcn_mfma_f32_16x16x32_bf16(pf, ones, ol, 0, 0, 0);
    }
    int qbase = qt * 64 + wave * 16 + quad * 4;
    size_t rb = (size_t)(bh * CK_ + ck) * L_;
#pragma unroll
    for (int r = 0; r < 4; r++) {
        po[(rb + qbase + r) * 32 + l15] = o0[r];
        po[(rb + qbase + r) * 32 + l15 + 16] = o1[r];
        if (l15 == 0) { pm[rb + qbase + r] = mrow[r]; pl[rb + qbase + r] = ol[r]; }
    }
}

// 7c) combine kv-chunk partials (max/alpha weighting) -> xo2b bf16 (BL,C)
__global__ void k_attn_red(const float* __restrict__ po, const float* __restrict__ pm,
                           const float* __restrict__ pl, short* __restrict__ xo2b) {
    int t = threadIdx.x;
    int grp = t >> 5, e = t & 31;
    int rowid = blockIdx.x * 8 + grp;
    int bh = rowid / L_, q = rowid % L_;
    size_t rb0 = (size_t)(bh * CK_) * L_ + q;
    float mm = -1e30f;
#pragma unroll
    for (int c = 0; c < CK_; c++) mm = fmaxf(mm, pm[rb0 + (size_t)c * L_]);
    float lsum = 0.f, acc = 0.f;
#pragma unroll
    for (int c = 0; c < CK_; c++) {
        float w = expf(pm[rb0 + (size_t)c * L_] - mm);
        lsum += w * pl[rb0 + (size_t)c * L_];
        acc += w * po[(rb0 + (size_t)c * L_) * 32 + e];
    }
    int b = bh >> 2, h = bh & 3;
    xo2b[((size_t)b * L_ + q) * C_ + h * 32 + e] = f2bf(acc / lsum);
}

// ---------------------------------------------------------------------------
// 10) ghost cheap branch + assemble output + residual
__global__ void k_ghost2(const float* __restrict__ pcl, const float* __restrict__ g2w,
                         const float* __restrict__ g2b, const float* __restrict__ x,
                         float* __restrict__ out) {
    int h = blockIdx.x, b = blockIdx.y;
    __shared__ float tile[3][W_][64];
    int t = threadIdx.x;
    for (int rr = 0; rr < 3; rr++) {
        int hh = h - 1 + rr;
        for (int i = 0; i < 12; i++) {
            int idx = t + i * 256;
            int w = idx >> 6, cc = idx & 63;
            tile[rr][w][cc] = (hh >= 0 && hh < H_) ? pcl[(size_t)(b * L_ + hh * W_ + w) * 64 + cc] : 0.f;
        }
    }
    __syncthreads();
    int cc = t & 63, wg = t >> 6;
    float w9[9];
#pragma unroll
    for (int i = 0; i < 9; i++) w9[i] = g2w[cc * 9 + i];
    float bias = g2b[cc];
    for (int w = wg; w < W_; w += 4) {
        int pos = h * W_ + w;
        float pv = tile[1][w][cc];
        out[(size_t)(b * C_ + cc) * L_ + pos] = pv + x[(size_t)(b * C_ + cc) * L_ + pos];
        float s = bias;
#pragma unroll
        for (int rr = 0; rr < 3; rr++)
#pragma unroll
            for (int c2 = 0; c2 < 3; c2++) {
                int ww = w - 1 + c2;
                if (ww >= 0 && ww < W_) s += tile[rr][ww][cc] * w9[rr * 3 + c2];
            }
        s = fmaxf(s, 0.f);
        out[(size_t)(b * C_ + 64 + cc) * L_ + pos] = s + x[(size_t)(b * C_ + 64 + cc) * L_ + pos];
    }
}

// ---------------------------------------------------------------------------
extern "C" void kernel_launch(void* const* d_in, const int* in_sizes, int n_in,
                              void* d_out, int out_size, void* d_ws, size_t ws_size,
                              hipStream_t stream) {
    const float* x        = (const float*)d_in[0];
    const float* norm_g   = (const float*)d_in[1];
    const float* norm_b   = (const float*)d_in[2];
    const float* in_w     = (const float*)d_in[3];
    const float* in_b     = (const float*)d_in[4];
    const float* conv_w   = (const float*)d_in[5];
    const float* conv_b   = (const float*)d_in[6];
    const float* xpw      = (const float*)d_in[7];
    const float* dtw      = (const float*)d_in[8];
    const float* dtb      = (const float*)d_in[9];
    const float* A_log    = (const float*)d_in[10];
    const float* Ds       = (const float*)d_in[11];
    const float* out_g    = (const float*)d_in[12];
    const float* out_b    = (const float*)d_in[13];
    const float* opw      = (const float*)d_in[14];
    const float* opb      = (const float*)d_in[15];
    const float* g1w      = (const float*)d_in[16];
    const float* g1b      = (const float*)d_in[17];
    const float* g2w      = (const float*)d_in[18];
    const float* g2b      = (const float*)d_in[19];
    float* out = (float*)d_out;

    float* ws = (float*)d_ws;
    size_t off = 0;
    float* xz    = ws + off; off += (size_t)BL_ * 2 * D_;      // 2359296
    float* xcl   = ws + off; off += (size_t)BL_ * D_;          // 1179648
    float* dts   = ws + off; off += (size_t)B_ * K_ * L_ * D_; // 4718592 (po alias)
    float* Bss   = ws + off; off += (size_t)B_ * K_ * L_ * N_; // 294912 (pcl alias)
    float* Css   = ws + off; off += (size_t)B_ * K_ * L_ * N_; // 294912
    float* ys    = ws + off; off += (size_t)B_ * K_ * L_ * D_; // 4718592 (P4 + xob alias)
    float* xo    = ws + off; off += (size_t)BL_ * C_;          // 589824
    float* hend  = ws + off; off += (size_t)B_ * K_ * S_ * D_ * N_; // 2097152 (pm/pl alias)
    float* sumdt = ws + off; off += (size_t)B_ * K_ * S_ * D_; // 131072
    short* xnb   = (short*)(ws + off); off += (size_t)BL_ * C_ / 2;
    short* xclb  = (short*)(ws + off); off += (size_t)BL_ * D_ / 2;
    short* ylnb  = (short*)(ws + off); off += (size_t)BL_ * D_ / 2;
    short* xo2b  = (short*)(ws + off); off += (size_t)BL_ * C_ / 2;
    short* wbf   = (short*)(ws + off); off += 147456 / 2;

    short* in_wb = wbf;
    short* xpwb  = wbf + 512 * 128;
    short* opwb  = xpwb + 160 * 256;
    short* g1wb  = opwb + 128 * 256;

    float* P4 = ys;  // alias: dead before scan pass C writes ys
    // attention scratch (all host regions dead by the time attention runs):
    //   xob (294912 f-slots) -> ys   (dead after k_combine)
    //   po  (4718592 f, == dts size) -> dts  (dead after k_scan_c)
    //   pm/pl (147456 f each)        -> hend (2097152 f, dead after k_scan_c)
    short* xob = (short*)ys;
    float* po  = dts;
    float* pmb = hend;
    float* plb = hend + 147456;
    float* pcl = Bss;  // alias: Bss dead after scan pass C

    k_tobf4<<<dim3(576), 256, 0, stream>>>(in_w, xpw, opw, g1w, in_wb, xpwb, opwb, g1wb);
    k_ln<<<dim3(L_ / 16, B_), 256, 0, stream>>>(x, norm_g, norm_b, xnb);
    k_bgemm<0, true><<<dim3(8, BL_ / 64), 256, 0, stream>>>(xnb, in_wb, in_b, xz, BL_, 512, C_);
    k_dwconv<<<dim3(D_ / 64, H_, B_), 256, 0, stream>>>(xz, conv_w, conv_b, xcl, xclb);
    k_bgemm<0, false><<<dim3(3, BL_ / 64), 256, 0, stream>>>(xclb, xpwb, nullptr, P4, BL_, 160, D_);
    k_xproj2<<<dim3(L_, K_, B_), 256, 0, stream>>>(P4, dtw, dtb, dts, Bss, Css);
    k_scan_a<<<dim3(S_, K_, B_), 256, 0, stream>>>(dts, Bss, xcl, A_log, hend, sumdt);
    k_scan_b<<<dim3(128), 256, 0, stream>>>(hend, sumdt, A_log);
    k_scan_c<<<dim3(S_, K_, B_), 256, 0, stream>>>(dts, Bss, Css, xcl, A_log, hend, ys);
    k_combine<<<dim3(BL_), 256, 0, stream>>>(ys, xcl, Ds, xz, out_g, out_b, ylnb);
    k_bgemm<0, true><<<dim3(2, BL_ / 64), 256, 0, stream>>>(ylnb, opwb, opb, xo, BL_, C_, D_);
    k_qbf<<<dim3(BL_ / 2), 256, 0, stream>>>(xo, xob);
    k_attn_mfma<<<dim3(L_ / 64, 8, CK_), 256, 0, stream>>>(xob, po, pmb, plb);
    k_attn_red<<<dim3(2304), 256, 0, stream>>>(po, pmb, plb, xo2b);
    k_bgemm<1, true><<<dim3(1, BL_ / 64), 256, 0, stream>>>(xo2b, g1wb, g1b, pcl, BL_, 64, C_);
    k_ghost2<<<dim3(H_, B_), 256, 0, stream>>>(pcl, g2w, g2b, x, out);
}